// Round 10
// baseline (1609.905 us; speedup 1.0000x reference)
//
#include <hip/hip_runtime.h>

#define D_ 2048
#define H_ 1408
#define E_ 16
#define T_ 16384
#define K_ 4
#define TK_ 65536
#define BM_ 256
#define BK_ 64
#define MAXT_ 272
#define CVTB_ 408   // W2-cvt blocks fused into gemm1 launch (51 per XCD)

typedef __attribute__((ext_vector_type(8))) short bf16x8;
typedef __attribute__((ext_vector_type(4))) float f32x4;
typedef __attribute__((ext_vector_type(4))) unsigned short u16x4;

#define M_NT     49
#define M_TE     64
#define M_TR     (64 + MAXT_)
#define M_TN     (64 + 2*MAXT_)

#define XB_OFF   0ULL
#define W1B_OFF  67108864ULL                      // T*D*2
#define W2B_OFF  (W1B_OFF + 188743680ULL)
#define ACT_OFF  (W2B_OFF + 94371840ULL)
#define PERM_OFF (ACT_OFF + 184549376ULL)         // TK*H*2
#define WGT_OFF  (PERM_OFF + 262144ULL)
#define META_B   (WGT_OFF + 262144ULL)

#define SBAR()  __builtin_amdgcn_s_barrier()
#define SCHED() __builtin_amdgcn_sched_barrier(0)
#define LGK0()  asm volatile("s_waitcnt lgkmcnt(0)" ::: "memory")
#define LGK2()  asm volatile("s_waitcnt lgkmcnt(2)" ::: "memory")
#define LGK4()  asm volatile("s_waitcnt lgkmcnt(4)" ::: "memory")
#define LGK6()  asm volatile("s_waitcnt lgkmcnt(6)" ::: "memory")
#define VM6()   asm volatile("s_waitcnt vmcnt(6)" ::: "memory")
#define PRIO1() __builtin_amdgcn_s_setprio(1)
#define PRIO0() __builtin_amdgcn_s_setprio(0)

static __device__ __forceinline__ unsigned short f2bf(float f) {
  unsigned u = __builtin_bit_cast(unsigned, f);
  u += 0x7fffu + ((u >> 16) & 1u);
  return (unsigned short)(u >> 16);
}

static __device__ __forceinline__ void gload16(const void* g, unsigned ldsOff) {
  __builtin_amdgcn_global_load_lds(
      (const __attribute__((address_space(1))) unsigned int*)(unsigned long long)g,
      (__attribute__((address_space(3))) unsigned int*)(unsigned long long)ldsOff,
      16, 0, 0);
}

// ---------------- prep: zero y + cvt x + cvt W1 (streaming blocks); last block: full routing
__global__ __launch_bounds__(1024) void prep_kernel(
    const float* __restrict__ x, const float* __restrict__ W1,
    const int* __restrict__ idx, const float* __restrict__ wts,
    float* __restrict__ y, unsigned short* __restrict__ xb,
    unsigned short* __restrict__ w1b, int* __restrict__ meta,
    int* __restrict__ perm, float* __restrict__ wgt) {
  const int tid = threadIdx.x;
  if (blockIdx.x == gridDim.x - 1) {
    __shared__ int cnt[E_], cur[E_];
    if (tid < E_) cnt[tid] = 0;
    __syncthreads();
    for (int i = tid; i < TK_; i += 1024) atomicAdd(&cnt[idx[i]], 1);
    __syncthreads();
    if (tid == 0) {
      int off = 0, nt = 0;
      for (int e = 0; e < E_; ++e) {
        cur[e] = off;
        const int c = cnt[e];
        for (int r = 0; r < c; r += BM_) {
          meta[M_TE + nt] = e;
          meta[M_TR + nt] = off + r;
          meta[M_TN + nt] = (c - r < BM_) ? (c - r) : BM_;
          ++nt;
        }
        off += c;
      }
      meta[M_NT] = nt;
    }
    __syncthreads();
    for (int i = tid; i < TK_; i += 1024) {
      const int pos = atomicAdd(&cur[idx[i]], 1);
      perm[pos] = i >> 2;
      wgt[pos] = wts[i];
    }
    return;
  }
  const long long base = ((long long)blockIdx.x * 1024 + tid) * 4;
  const long long stride = (long long)(gridDim.x - 1) * 1024 * 4;
  for (long long i = base; i < (long long)T_ * D_; i += stride)
    *reinterpret_cast<float4*>(y + i) = (float4){0.f, 0.f, 0.f, 0.f};
  for (long long i = base; i < (long long)T_ * D_; i += stride) {
    float4 v = *reinterpret_cast<const float4*>(x + i);
    u16x4 o = { f2bf(v.x), f2bf(v.y), f2bf(v.z), f2bf(v.w) };
    *reinterpret_cast<u16x4*>(xb + i) = o;
  }
  for (long long i = base; i < (long long)E_ * 2 * H_ * D_; i += stride) {
    float4 v = *reinterpret_cast<const float4*>(W1 + i);
    u16x4 o = { f2bf(v.x), f2bf(v.y), f2bf(v.z), f2bf(v.w) };
    *reinterpret_cast<u16x4*>(w1b + i) = o;
  }
}

// ---------------- GEMM1 (+fused W2 cvt): 256 rows x (128 u + 128 g), 4-phase,
// 4 barriers/K-tile, one-phase ds_read-ahead (compiler-counted lgkm waits)
__global__ __launch_bounds__(512, 2) void gemm1_kernel(
    const char* __restrict__ xb, const char* __restrict__ w1b,
    const int* __restrict__ perm, const int* __restrict__ meta,
    unsigned short* __restrict__ act,
    const float* __restrict__ W2, unsigned short* __restrict__ w2b) {
  const int tid = threadIdx.x;
  const int bid0 = (int)blockIdx.x;
  if (bid0 < CVTB_) {  // W2 conversion role (dispatched first, 51/XCD)
    long long i = ((long long)bid0 * 512 + tid) * 4;
    const long long stride = (long long)CVTB_ * 512 * 4;
    for (; i < (long long)E_ * D_ * H_; i += stride) {
      float4 v = *reinterpret_cast<const float4*>(W2 + i);
      u16x4 o = { f2bf(v.x), f2bf(v.y), f2bf(v.z), f2bf(v.w) };
      *reinterpret_cast<u16x4*>(w2b + i) = o;
    }
    return;
  }
  __shared__ char lds[131072];
  int bid = bid0 - CVTB_;
  bid = (bid & 7) * 374 + (bid >> 3);  // XCD-chunked over 2992 (2992/8=374)
  const int tb = bid / 11;
  const int cb = bid - tb * 11;
  if (tb >= meta[M_NT]) return;
  const int e = meta[M_TE + tb];
  const int row0 = meta[M_TR + tb];
  const int nrows = meta[M_TN + tb];
  const int lane = tid & 63, wid = tid >> 6;
  const int wr = wid >> 2, wc = wid & 3;
  const unsigned ldsBase = (unsigned)(unsigned long long)&lds[0];
  constexpr int NT = D_ / BK_;  // 32

  const char* aSrc[4];
  const char* bSrc[4];
  {
    const int r8 = tid >> 3;
    const unsigned colb0 = (unsigned)(tid & 7) * 16u;
#pragma unroll
    for (int i = 0; i < 4; ++i) {
      const int r = r8 + i * 64;
      const unsigned colb = colb0 ^ ((unsigned)(r & 7) << 4);
      const int rc = (r < nrows) ? r : 0;
      aSrc[i] = xb + (size_t)perm[row0 + rc] * 4096 + colb;
      const int w1row = (i < 2) ? (cb * 128 + r) : (H_ + cb * 128 + (r - 128));
      bSrc[i] = w1b + (size_t)e * (2 * H_) * 4096ULL + (size_t)w1row * 4096 + colb;
    }
  }

  const int l15 = lane & 15, hi = lane >> 4;
  const unsigned swz = (unsigned)(l15 & 7) << 4;
  unsigned aOff[8], bOffU[2], bOffG[2];
#pragma unroll
  for (int m = 0; m < 8; ++m) {
    const int row = wr * 128 + m * 16 + l15;
    aOff[m] = (unsigned)(row * 128) + (((unsigned)hi * 16u) ^ swz);
  }
#pragma unroll
  for (int n = 0; n < 2; ++n) {
    const int ru = wc * 32 + n * 16 + l15;
    bOffU[n] = 65536u + (unsigned)(ru * 128) + (((unsigned)hi * 16u) ^ swz);
    const int rg = ru + 128;
    bOffG[n] = 65536u + (unsigned)(rg * 128) + (((unsigned)hi * 16u) ^ swz);
  }

  f32x4 aU[8][2], aG[8][2];
#pragma unroll
  for (int m = 0; m < 8; ++m)
#pragma unroll
    for (int n = 0; n < 2; ++n) {
      aU[m][n] = (f32x4){0.f, 0.f, 0.f, 0.f};
      aG[m][n] = (f32x4){0.f, 0.f, 0.f, 0.f};
    }

  auto STAGE_A = [&](int t, int h) {
    const int tt = (t < NT) ? t : (NT - 1);
    const size_t kb = (size_t)tt * 128;
    const unsigned dst = ldsBase + (unsigned)(t & 1) * 32768u + (unsigned)h * 16384u + (unsigned)tid * 16u;
    gload16(aSrc[h * 2 + 0] + kb, dst);
    gload16(aSrc[h * 2 + 1] + kb, dst + 8192u);
  };
  auto STAGE_B = [&](int t, int h) {
    const int tt = (t < NT) ? t : (NT - 1);
    const size_t kb = (size_t)tt * 128;
    const unsigned dst = ldsBase + 65536u + (unsigned)(t & 1) * 32768u + (unsigned)h * 16384u + (unsigned)tid * 16u;
    gload16(bSrc[h * 2 + 0] + kb, dst);
    gload16(bSrc[h * 2 + 1] + kb, dst + 8192u);
  };

  STAGE_B(0, 0); STAGE_B(0, 1); STAGE_A(0, 0); STAGE_A(0, 1);
  STAGE_B(1, 0); STAGE_B(1, 1); STAGE_A(1, 0);
  VM6(); SCHED(); SBAR();

  bf16x8 aLo[4][2], aHi[4][2], bu[2][2], bg[2][2];
  // prologue prefetch: tile0 aLo+bu from buf0
#pragma unroll
  for (int ks = 0; ks < 2; ++ks) {
#pragma unroll
    for (int m = 0; m < 4; ++m)
      aLo[m][ks] = *reinterpret_cast<const bf16x8*>(lds + (aOff[m] ^ (unsigned)(ks << 6)));
#pragma unroll
    for (int n = 0; n < 2; ++n)
      bu[n][ks] = *reinterpret_cast<const bf16x8*>(lds + (bOffU[n] ^ (unsigned)(ks << 6)));
  }

  for (int t = 0; t < NT; ++t) {
    const char* base = lds + (unsigned)(t & 1) * 32768u;
    const char* nbase = lds + (unsigned)((t + 1) & 1) * 32768u;

    // ph0: read bg(t); stage A(t+1,h1); MFMA aU-lo (aLo x bu, prefetched); SBAR
#pragma unroll
    for (int ks = 0; ks < 2; ++ks)
#pragma unroll
      for (int n = 0; n < 2; ++n)
        bg[n][ks] = *reinterpret_cast<const bf16x8*>(base + (bOffG[n] ^ (unsigned)(ks << 6)));
    STAGE_A(t + 1, 1);
    SCHED();
    PRIO1();
#pragma unroll
    for (int ks = 0; ks < 2; ++ks)
#pragma unroll
      for (int m = 0; m < 4; ++m)
#pragma unroll
        for (int n = 0; n < 2; ++n)
          aU[m][n] = __builtin_amdgcn_mfma_f32_16x16x32_bf16(aLo[m][ks], bu[n][ks], aU[m][n], 0, 0, 0);
    PRIO0(); SCHED(); SBAR();

    // ph1: read aHi(t); stage B(t+2,h0); MFMA aG-lo (aLo x bg); SBAR
#pragma unroll
    for (int ks = 0; ks < 2; ++ks)
#pragma unroll
      for (int m = 0; m < 4; ++m)
        aHi[m][ks] = *reinterpret_cast<const bf16x8*>(base + (aOff[4 + m] ^ (unsigned)(ks << 6)));
    STAGE_B(t + 2, 0);
    SCHED();
    PRIO1();
#pragma unroll
    for (int ks = 0; ks < 2; ++ks)
#pragma unroll
      for (int m = 0; m < 4; ++m)
#pragma unroll
        for (int n = 0; n < 2; ++n)
          aG[m][n] = __builtin_amdgcn_mfma_f32_16x16x32_bf16(aLo[m][ks], bg[n][ks], aG[m][n], 0, 0, 0);
    PRIO0(); SCHED(); SBAR();

    // ph2: stage B(t+2,h1); MFMA aU-hi (aHi x bu); SBAR
    STAGE_B(t + 2, 1);
    SCHED();
    PRIO1();
#pragma unroll
    for (int ks = 0; ks < 2; ++ks)
#pragma unroll
      for (int m = 0; m < 4; ++m)
#pragma unroll
        for (int n = 0; n < 2; ++n)
          aU[4 + m][n] = __builtin_amdgcn_mfma_f32_16x16x32_bf16(aHi[m][ks], bu[n][ks], aU[4 + m][n], 0, 0, 0);
    PRIO0(); SCHED(); SBAR();

    // ph3: stage A(t+2,h0); VM6+SBAR (tile t+1 landed & visible);
    //      prefetch next aLo,bu from nbase; MFMA aG-hi (aHi x bg); no trailing barrier
    STAGE_A(t + 2, 0);
    VM6(); SCHED(); SBAR();
#pragma unroll
    for (int ks = 0; ks < 2; ++ks) {
#pragma unroll
      for (int m = 0; m < 4; ++m)
        aLo[m][ks] = *reinterpret_cast<const bf16x8*>(nbase + (aOff[m] ^ (unsigned)(ks << 6)));
#pragma unroll
      for (int n = 0; n < 2; ++n)
        bu[n][ks] = *reinterpret_cast<const bf16x8*>(nbase + (bOffU[n] ^ (unsigned)(ks << 6)));
    }
    SCHED();
    PRIO1();
#pragma unroll
    for (int ks = 0; ks < 2; ++ks)
#pragma unroll
      for (int m = 0; m < 4; ++m)
#pragma unroll
        for (int n = 0; n < 2; ++n)
          aG[4 + m][n] = __builtin_amdgcn_mfma_f32_16x16x32_bf16(aHi[m][ks], bg[n][ks], aG[4 + m][n], 0, 0, 0);
    PRIO0(); SCHED();
  }

#pragma unroll
  for (int m = 0; m < 8; ++m)
#pragma unroll
    for (int j = 0; j < 4; ++j) {
      const int r = wr * 128 + m * 16 + hi * 4 + j;
      if (r < nrows) {
        const size_t rowBase = (size_t)(row0 + r) * H_ + (size_t)cb * 128 + (size_t)wc * 32;
#pragma unroll
        for (int n = 0; n < 2; ++n) {
          const float u = aU[m][n][j];
          const float g = aG[m][n][j];
          act[rowBase + n * 16 + l15] = f2bf(u * (g / (1.0f + __expf(-g))));
        }
      }
    }
}

// ---------------- GEMM2: 256 rows x 256 out cols, 4-phase/K-tile, 8 barriers/K-tile (R9 form, untouched)
__global__ __launch_bounds__(512, 2) void gemm2_kernel(
    const char* __restrict__ actb, const char* __restrict__ w2b,
    const int* __restrict__ perm, const float* __restrict__ wgt,
    const int* __restrict__ meta, float* __restrict__ y) {
  __shared__ char lds[131072];
  int bid = (int)blockIdx.x;
  bid = (bid & 7) * (int)(gridDim.x >> 3) + (bid >> 3);  // 2176%8==0
  const int tb = bid >> 3;
  const int cb = bid & 7;
  if (tb >= meta[M_NT]) return;
  const int e = meta[M_TE + tb];
  const int row0 = meta[M_TR + tb];
  const int nrows = meta[M_TN + tb];
  const int tid = threadIdx.x, lane = tid & 63, wid = tid >> 6;
  const int wr = wid >> 2, wc = wid & 3;
  const unsigned ldsBase = (unsigned)(unsigned long long)&lds[0];
  constexpr int NT = H_ / BK_;  // 22

  const char* aSrc[4];
  const char* bSrc[4];
  {
    const int r8 = tid >> 3;
    const unsigned colb0 = (unsigned)(tid & 7) * 16u;
#pragma unroll
    for (int i = 0; i < 4; ++i) {
      const int r = r8 + i * 64;
      const unsigned colb = colb0 ^ ((unsigned)(r & 7) << 4);
      const int rc = (r < nrows) ? r : 0;
      aSrc[i] = actb + (size_t)(row0 + rc) * (H_ * 2) + colb;
      const int brow = cb * 256 + r;
      bSrc[i] = w2b + (size_t)e * D_ * (H_ * 2) + (size_t)brow * (H_ * 2) + colb;
    }
  }

  const int l15 = lane & 15, hi = lane >> 4;
  const unsigned swz = (unsigned)(l15 & 7) << 4;
  unsigned aOff[8], bOff[4];
#pragma unroll
  for (int m = 0; m < 8; ++m) {
    const int row = wr * 128 + m * 16 + l15;
    aOff[m] = (unsigned)(row * 128) + (((unsigned)hi * 16u) ^ swz);
  }
#pragma unroll
  for (int n = 0; n < 4; ++n) {
    const int rb = wc * 64 + n * 16 + l15;
    bOff[n] = 65536u + (unsigned)(rb * 128) + (((unsigned)hi * 16u) ^ swz);
  }

  f32x4 acc[8][4];
#pragma unroll
  for (int m = 0; m < 8; ++m)
#pragma unroll
    for (int n = 0; n < 4; ++n) acc[m][n] = (f32x4){0.f, 0.f, 0.f, 0.f};

  auto STAGE_A = [&](int t, int h) {
    const int tt = (t < NT) ? t : (NT - 1);
    const size_t kb = (size_t)tt * 128;
    const unsigned dst = ldsBase + (unsigned)(t & 1) * 32768u + (unsigned)h * 16384u + (unsigned)tid * 16u;
    gload16(aSrc[h * 2 + 0] + kb, dst);
    gload16(aSrc[h * 2 + 1] + kb, dst + 8192u);
  };
  auto STAGE_B = [&](int t, int h) {
    const int tt = (t < NT) ? t : (NT - 1);
    const size_t kb = (size_t)tt * 128;
    const unsigned dst = ldsBase + 65536u + (unsigned)(t & 1) * 32768u + (unsigned)h * 16384u + (unsigned)tid * 16u;
    gload16(bSrc[h * 2 + 0] + kb, dst);
    gload16(bSrc[h * 2 + 1] + kb, dst + 8192u);
  };

  STAGE_B(0, 0); STAGE_B(0, 1); STAGE_A(0, 0); STAGE_A(0, 1);
  STAGE_B(1, 0); STAGE_B(1, 1); STAGE_A(1, 0);
  VM6(); SCHED(); SBAR();

  for (int t = 0; t < NT; ++t) {
    const char* base = lds + (unsigned)(t & 1) * 32768u;
    bf16x8 aLo[4][2], aHi[4][2], b[4][2];

    // phase 0
#pragma unroll
    for (int ks = 0; ks < 2; ++ks) {
#pragma unroll
      for (int m = 0; m < 4; ++m)
        aLo[m][ks] = *reinterpret_cast<const bf16x8*>(base + (aOff[m] ^ (unsigned)(ks << 6)));
#pragma unroll
      for (int n = 0; n < 2; ++n)
        b[n][ks] = *reinterpret_cast<const bf16x8*>(base + (bOff[n] ^ (unsigned)(ks << 6)));
    }
    STAGE_A(t + 1, 1);
    SCHED(); SBAR(); LGK6(); SCHED();
    PRIO1();
#pragma unroll
    for (int m = 0; m < 4; ++m)
#pragma unroll
      for (int n = 0; n < 2; ++n)
        acc[m][n] = __builtin_amdgcn_mfma_f32_16x16x32_bf16(aLo[m][0], b[n][0], acc[m][n], 0, 0, 0);
    LGK0(); SCHED();
#pragma unroll
    for (int m = 0; m < 4; ++m)
#pragma unroll
      for (int n = 0; n < 2; ++n)
        acc[m][n] = __builtin_amdgcn_mfma_f32_16x16x32_bf16(aLo[m][1], b[n][1], acc[m][n], 0, 0, 0);
    PRIO0(); SCHED(); SBAR();

    // phase 1
#pragma unroll
    for (int ks = 0; ks < 2; ++ks)
#pragma unroll
      for (int n = 2; n < 4; ++n)
        b[n][ks] = *reinterpret_cast<const bf16x8*>(base + (bOff[n] ^ (unsigned)(ks << 6)));
    STAGE_B(t + 2, 0);
    SCHED(); SBAR(); LGK2(); SCHED();
    PRIO1();
#pragma unroll
    for (int m = 0; m < 4; ++m)
#pragma unroll
      for (int n = 2; n < 4; ++n)
        acc[m][n] = __builtin_amdgcn_mfma_f32_16x16x32_bf16(aLo[m][0], b[n][0], acc[m][n], 0, 0, 0);
    LGK0(); SCHED();
#pragma unroll
    for (int m = 0; m < 4; ++m)
#pragma unroll
      for (int n = 2; n < 4; ++n)
        acc[m][n] = __builtin_amdgcn_mfma_f32_16x16x32_bf16(aLo[m][1], b[n][1], acc[m][n], 0, 0, 0);
    PRIO0(); SCHED(); SBAR();

    // phase 2
#pragma unroll
    for (int ks = 0; ks < 2; ++ks)
#pragma unroll
      for (int m = 0; m < 4; ++m)
        aHi[m][ks] = *reinterpret_cast<const bf16x8*>(base + (aOff[4 + m] ^ (unsigned)(ks << 6)));
    STAGE_B(t + 2, 1);
    SCHED(); SBAR(); LGK4(); SCHED();
    PRIO1();
#pragma unroll
    for (int m = 0; m < 4; ++m)
#pragma unroll
      for (int n = 0; n < 2; ++n)
        acc[4 + m][n] = __builtin_amdgcn_mfma_f32_16x16x32_bf16(aHi[m][0], b[n][0], acc[4 + m][n], 0, 0, 0);
    LGK0(); SCHED();
#pragma unroll
    for (int m = 0; m < 4; ++m)
#pragma unroll
      for (int n = 0; n < 2; ++n)
        acc[4 + m][n] = __builtin_amdgcn_mfma_f32_16x16x32_bf16(aHi[m][1], b[n][1], acc[4 + m][n], 0, 0, 0);
    PRIO0(); SCHED(); SBAR();

    // phase 3
    STAGE_A(t + 2, 0);
    VM6(); SCHED(); SBAR();
    PRIO1();
#pragma unroll
    for (int ks = 0; ks < 2; ++ks)
#pragma unroll
      for (int m = 0; m < 4; ++m)
#pragma unroll
        for (int n = 2; n < 4; ++n)
          acc[4 + m][n] = __builtin_amdgcn_mfma_f32_16x16x32_bf16(aHi[m][ks], b[n][ks], acc[4 + m][n], 0, 0, 0);
    PRIO0(); SCHED(); SBAR();
  }

#pragma unroll
  for (int m = 0; m < 8; ++m)
#pragma unroll
    for (int j = 0; j < 4; ++j) {
      const int r = wr * 128 + m * 16 + hi * 4 + j;
      if (r < nrows) {
        const float w = wgt[row0 + r];
        const int token = perm[row0 + r];
        float* yrow = y + (size_t)token * D_ + (size_t)cb * 256 + (size_t)wc * 64;
#pragma unroll
        for (int n = 0; n < 4; ++n)
          unsafeAtomicAdd(&yrow[n * 16 + l15], acc[m][n][j] * w);
      }
    }
}

extern "C" void kernel_launch(void* const* d_in, const int* in_sizes, int n_in,
                              void* d_out, int out_size, void* d_ws, size_t ws_size,
                              hipStream_t stream) {
  const float* x   = (const float*)d_in[0];
  const float* wts = (const float*)d_in[1];
  const int*   idx = (const int*)d_in[2];
  const float* W1  = (const float*)d_in[3];
  const float* W2  = (const float*)d_in[4];
  float* y = (float*)d_out;
  char* ws = (char*)d_ws;

  unsigned short* xb  = (unsigned short*)(ws + XB_OFF);
  unsigned short* w1b = (unsigned short*)(ws + W1B_OFF);
  unsigned short* w2b = (unsigned short*)(ws + W2B_OFF);
  unsigned short* act = (unsigned short*)(ws + ACT_OFF);
  int*   perm = (int*)(ws + PERM_OFF);
  float* wgt  = (float*)(ws + WGT_OFF);
  int*   meta = (int*)(ws + META_B);

  prep_kernel<<<2049, 1024, 0, stream>>>(x, W1, idx, wts, y, xb, w1b, meta, perm, wgt);

  gemm1_kernel<<<CVTB_ + MAXT_ * (H_ / 128), 512, 0, stream>>>(
      (const char*)xb, (const char*)w1b, perm, meta, act, W2, w2b);

  gemm2_kernel<<<MAXT_ * (D_ / 256), 512, 0, stream>>>(
      (const char*)act, (const char*)w2b, perm, wgt, meta, y);
}

// Round 11
// 1570.717 us; speedup vs baseline: 1.0249x; 1.0249x over previous
//
#include <hip/hip_runtime.h>

#define D_ 2048
#define H_ 1408
#define E_ 16
#define T_ 16384
#define K_ 4
#define TK_ 65536
#define BM_ 256
#define BK_ 64
#define MAXT_ 272
#define CVTB_ 408   // W2-cvt blocks fused into gemm1 launch (51 per XCD)

typedef __attribute__((ext_vector_type(8))) short bf16x8;
typedef __attribute__((ext_vector_type(4))) float f32x4;
typedef __attribute__((ext_vector_type(4))) unsigned short u16x4;

#define M_NT     49
#define M_TE     64
#define M_TR     (64 + MAXT_)
#define M_TN     (64 + 2*MAXT_)

#define XB_OFF   0ULL
#define W1B_OFF  67108864ULL                      // T*D*2
#define W2B_OFF  (W1B_OFF + 188743680ULL)
#define ACT_OFF  (W2B_OFF + 94371840ULL)
#define PERM_OFF (ACT_OFF + 184549376ULL)         // TK*H*2
#define WGT_OFF  (PERM_OFF + 262144ULL)
#define META_B   (WGT_OFF + 262144ULL)

#define SBAR()  __builtin_amdgcn_s_barrier()
#define SCHED() __builtin_amdgcn_sched_barrier(0)
#define VM0()   asm volatile("s_waitcnt vmcnt(0)" ::: "memory")
#define VM6()   asm volatile("s_waitcnt vmcnt(6)" ::: "memory")
#define PRIO1() __builtin_amdgcn_s_setprio(1)
#define PRIO0() __builtin_amdgcn_s_setprio(0)

static __device__ __forceinline__ unsigned short f2bf(float f) {
  unsigned u = __builtin_bit_cast(unsigned, f);
  u += 0x7fffu + ((u >> 16) & 1u);
  return (unsigned short)(u >> 16);
}

static __device__ __forceinline__ void gload16(const void* g, unsigned ldsOff) {
  __builtin_amdgcn_global_load_lds(
      (const __attribute__((address_space(1))) unsigned int*)(unsigned long long)g,
      (__attribute__((address_space(3))) unsigned int*)(unsigned long long)ldsOff,
      16, 0, 0);
}

// ---------------- prep: zero y + cvt x + cvt W1 (streaming blocks); last block: full routing
__global__ __launch_bounds__(1024) void prep_kernel(
    const float* __restrict__ x, const float* __restrict__ W1,
    const int* __restrict__ idx, const float* __restrict__ wts,
    float* __restrict__ y, unsigned short* __restrict__ xb,
    unsigned short* __restrict__ w1b, int* __restrict__ meta,
    int* __restrict__ perm, float* __restrict__ wgt) {
  const int tid = threadIdx.x;
  if (blockIdx.x == gridDim.x - 1) {
    __shared__ int cnt[E_], cur[E_];
    if (tid < E_) cnt[tid] = 0;
    __syncthreads();
    for (int i = tid; i < TK_; i += 1024) atomicAdd(&cnt[idx[i]], 1);
    __syncthreads();
    if (tid == 0) {
      int off = 0, nt = 0;
      for (int e = 0; e < E_; ++e) {
        cur[e] = off;
        const int c = cnt[e];
        for (int r = 0; r < c; r += BM_) {
          meta[M_TE + nt] = e;
          meta[M_TR + nt] = off + r;
          meta[M_TN + nt] = (c - r < BM_) ? (c - r) : BM_;
          ++nt;
        }
        off += c;
      }
      meta[M_NT] = nt;
    }
    __syncthreads();
    for (int i = tid; i < TK_; i += 1024) {
      const int pos = atomicAdd(&cur[idx[i]], 1);
      perm[pos] = i >> 2;
      wgt[pos] = wts[i];
    }
    return;
  }
  const long long base = ((long long)blockIdx.x * 1024 + tid) * 4;
  const long long stride = (long long)(gridDim.x - 1) * 1024 * 4;
  for (long long i = base; i < (long long)T_ * D_; i += stride)
    *reinterpret_cast<float4*>(y + i) = (float4){0.f, 0.f, 0.f, 0.f};
  for (long long i = base; i < (long long)T_ * D_; i += stride) {
    float4 v = *reinterpret_cast<const float4*>(x + i);
    u16x4 o = { f2bf(v.x), f2bf(v.y), f2bf(v.z), f2bf(v.w) };
    *reinterpret_cast<u16x4*>(xb + i) = o;
  }
  for (long long i = base; i < (long long)E_ * 2 * H_ * D_; i += stride) {
    float4 v = *reinterpret_cast<const float4*>(W1 + i);
    u16x4 o = { f2bf(v.x), f2bf(v.y), f2bf(v.z), f2bf(v.w) };
    *reinterpret_cast<u16x4*>(w1b + i) = o;
  }
}

// ---------------- GEMM1 (+fused W2 cvt): 256 rows x (128 u + 128 g), 4-phase,
// 4 barriers/K-tile, one-phase ds_read-ahead (R10 form, unchanged)
__global__ __launch_bounds__(512, 2) void gemm1_kernel(
    const char* __restrict__ xb, const char* __restrict__ w1b,
    const int* __restrict__ perm, const int* __restrict__ meta,
    unsigned short* __restrict__ act,
    const float* __restrict__ W2, unsigned short* __restrict__ w2b) {
  const int tid = threadIdx.x;
  const int bid0 = (int)blockIdx.x;
  if (bid0 < CVTB_) {
    long long i = ((long long)bid0 * 512 + tid) * 4;
    const long long stride = (long long)CVTB_ * 512 * 4;
    for (; i < (long long)E_ * D_ * H_; i += stride) {
      float4 v = *reinterpret_cast<const float4*>(W2 + i);
      u16x4 o = { f2bf(v.x), f2bf(v.y), f2bf(v.z), f2bf(v.w) };
      *reinterpret_cast<u16x4*>(w2b + i) = o;
    }
    return;
  }
  __shared__ char lds[131072];
  int bid = bid0 - CVTB_;
  bid = (bid & 7) * 374 + (bid >> 3);
  const int tb = bid / 11;
  const int cb = bid - tb * 11;
  if (tb >= meta[M_NT]) return;
  const int e = meta[M_TE + tb];
  const int row0 = meta[M_TR + tb];
  const int nrows = meta[M_TN + tb];
  const int lane = tid & 63, wid = tid >> 6;
  const int wr = wid >> 2, wc = wid & 3;
  const unsigned ldsBase = (unsigned)(unsigned long long)&lds[0];
  constexpr int NT = D_ / BK_;  // 32

  const char* aSrc[4];
  const char* bSrc[4];
  {
    const int r8 = tid >> 3;
    const unsigned colb0 = (unsigned)(tid & 7) * 16u;
#pragma unroll
    for (int i = 0; i < 4; ++i) {
      const int r = r8 + i * 64;
      const unsigned colb = colb0 ^ ((unsigned)(r & 7) << 4);
      const int rc = (r < nrows) ? r : 0;
      aSrc[i] = xb + (size_t)perm[row0 + rc] * 4096 + colb;
      const int w1row = (i < 2) ? (cb * 128 + r) : (H_ + cb * 128 + (r - 128));
      bSrc[i] = w1b + (size_t)e * (2 * H_) * 4096ULL + (size_t)w1row * 4096 + colb;
    }
  }

  const int l15 = lane & 15, hi = lane >> 4;
  const unsigned swz = (unsigned)(l15 & 7) << 4;
  unsigned aOff[8], bOffU[2], bOffG[2];
#pragma unroll
  for (int m = 0; m < 8; ++m) {
    const int row = wr * 128 + m * 16 + l15;
    aOff[m] = (unsigned)(row * 128) + (((unsigned)hi * 16u) ^ swz);
  }
#pragma unroll
  for (int n = 0; n < 2; ++n) {
    const int ru = wc * 32 + n * 16 + l15;
    bOffU[n] = 65536u + (unsigned)(ru * 128) + (((unsigned)hi * 16u) ^ swz);
    const int rg = ru + 128;
    bOffG[n] = 65536u + (unsigned)(rg * 128) + (((unsigned)hi * 16u) ^ swz);
  }

  f32x4 aU[8][2], aG[8][2];
#pragma unroll
  for (int m = 0; m < 8; ++m)
#pragma unroll
    for (int n = 0; n < 2; ++n) {
      aU[m][n] = (f32x4){0.f, 0.f, 0.f, 0.f};
      aG[m][n] = (f32x4){0.f, 0.f, 0.f, 0.f};
    }

  auto STAGE_A = [&](int t, int h) {
    const int tt = (t < NT) ? t : (NT - 1);
    const size_t kb = (size_t)tt * 128;
    const unsigned dst = ldsBase + (unsigned)(t & 1) * 32768u + (unsigned)h * 16384u + (unsigned)tid * 16u;
    gload16(aSrc[h * 2 + 0] + kb, dst);
    gload16(aSrc[h * 2 + 1] + kb, dst + 8192u);
  };
  auto STAGE_B = [&](int t, int h) {
    const int tt = (t < NT) ? t : (NT - 1);
    const size_t kb = (size_t)tt * 128;
    const unsigned dst = ldsBase + 65536u + (unsigned)(t & 1) * 32768u + (unsigned)h * 16384u + (unsigned)tid * 16u;
    gload16(bSrc[h * 2 + 0] + kb, dst);
    gload16(bSrc[h * 2 + 1] + kb, dst + 8192u);
  };

  STAGE_B(0, 0); STAGE_B(0, 1); STAGE_A(0, 0); STAGE_A(0, 1);
  STAGE_B(1, 0); STAGE_B(1, 1); STAGE_A(1, 0);
  VM6(); SCHED(); SBAR();

  bf16x8 aLo[4][2], aHi[4][2], bu[2][2], bg[2][2];
#pragma unroll
  for (int ks = 0; ks < 2; ++ks) {
#pragma unroll
    for (int m = 0; m < 4; ++m)
      aLo[m][ks] = *reinterpret_cast<const bf16x8*>(lds + (aOff[m] ^ (unsigned)(ks << 6)));
#pragma unroll
    for (int n = 0; n < 2; ++n)
      bu[n][ks] = *reinterpret_cast<const bf16x8*>(lds + (bOffU[n] ^ (unsigned)(ks << 6)));
  }

  for (int t = 0; t < NT; ++t) {
    const char* base = lds + (unsigned)(t & 1) * 32768u;
    const char* nbase = lds + (unsigned)((t + 1) & 1) * 32768u;

#pragma unroll
    for (int ks = 0; ks < 2; ++ks)
#pragma unroll
      for (int n = 0; n < 2; ++n)
        bg[n][ks] = *reinterpret_cast<const bf16x8*>(base + (bOffG[n] ^ (unsigned)(ks << 6)));
    STAGE_A(t + 1, 1);
    SCHED();
    PRIO1();
#pragma unroll
    for (int ks = 0; ks < 2; ++ks)
#pragma unroll
      for (int m = 0; m < 4; ++m)
#pragma unroll
        for (int n = 0; n < 2; ++n)
          aU[m][n] = __builtin_amdgcn_mfma_f32_16x16x32_bf16(aLo[m][ks], bu[n][ks], aU[m][n], 0, 0, 0);
    PRIO0(); SCHED(); SBAR();

#pragma unroll
    for (int ks = 0; ks < 2; ++ks)
#pragma unroll
      for (int m = 0; m < 4; ++m)
        aHi[m][ks] = *reinterpret_cast<const bf16x8*>(base + (aOff[4 + m] ^ (unsigned)(ks << 6)));
    STAGE_B(t + 2, 0);
    SCHED();
    PRIO1();
#pragma unroll
    for (int ks = 0; ks < 2; ++ks)
#pragma unroll
      for (int m = 0; m < 4; ++m)
#pragma unroll
        for (int n = 0; n < 2; ++n)
          aG[m][n] = __builtin_amdgcn_mfma_f32_16x16x32_bf16(aLo[m][ks], bg[n][ks], aG[m][n], 0, 0, 0);
    PRIO0(); SCHED(); SBAR();

    STAGE_B(t + 2, 1);
    SCHED();
    PRIO1();
#pragma unroll
    for (int ks = 0; ks < 2; ++ks)
#pragma unroll
      for (int m = 0; m < 4; ++m)
#pragma unroll
        for (int n = 0; n < 2; ++n)
          aU[4 + m][n] = __builtin_amdgcn_mfma_f32_16x16x32_bf16(aHi[m][ks], bu[n][ks], aU[4 + m][n], 0, 0, 0);
    PRIO0(); SCHED(); SBAR();

    STAGE_A(t + 2, 0);
    VM6(); SCHED(); SBAR();
#pragma unroll
    for (int ks = 0; ks < 2; ++ks) {
#pragma unroll
      for (int m = 0; m < 4; ++m)
        aLo[m][ks] = *reinterpret_cast<const bf16x8*>(nbase + (aOff[m] ^ (unsigned)(ks << 6)));
#pragma unroll
      for (int n = 0; n < 2; ++n)
        bu[n][ks] = *reinterpret_cast<const bf16x8*>(nbase + (bOffU[n] ^ (unsigned)(ks << 6)));
    }
    SCHED();
    PRIO1();
#pragma unroll
    for (int ks = 0; ks < 2; ++ks)
#pragma unroll
      for (int m = 0; m < 4; ++m)
#pragma unroll
        for (int n = 0; n < 2; ++n)
          aG[4 + m][n] = __builtin_amdgcn_mfma_f32_16x16x32_bf16(aHi[m][ks], bg[n][ks], aG[4 + m][n], 0, 0, 0);
    PRIO0(); SCHED();
  }

#pragma unroll
  for (int m = 0; m < 8; ++m)
#pragma unroll
    for (int j = 0; j < 4; ++j) {
      const int r = wr * 128 + m * 16 + hi * 4 + j;
      if (r < nrows) {
        const size_t rowBase = (size_t)(row0 + r) * H_ + (size_t)cb * 128 + (size_t)wc * 32;
#pragma unroll
        for (int n = 0; n < 2; ++n) {
          const float u = aU[m][n][j];
          const float g = aG[m][n][j];
          act[rowBase + n * 16 + l15] = f2bf(u * (g / (1.0f + __expf(-g))));
        }
      }
    }
}

// ---------------- GEMM2: m97-style 128x128 tile, BK=64, single 32KB buffer,
// 2 barriers/K-tile, ~3 blocks/CU co-residency. 256 thr, 4 waves (2x2, 64x64/wave).
__global__ __launch_bounds__(256) void gemm2_kernel(
    const char* __restrict__ actb, const char* __restrict__ w2b,
    const int* __restrict__ perm, const float* __restrict__ wgt,
    const int* __restrict__ meta, float* __restrict__ y) {
  __shared__ char lds[32768];  // A: [0,16K) 128 rows x 128B; B: [16K,32K)
  int bid = (int)blockIdx.x;
  bid = (bid & 7) * ((int)gridDim.x >> 3) + (bid >> 3);  // 8704%8==0
  const int st = bid >> 4;     // row subtile (128 rows)
  const int cb = bid & 15;     // 128-col block of D
  const int tb = st >> 1, half = st & 1;
  if (tb >= meta[M_NT]) return;
  const int nrA = meta[M_TN + tb] - half * 128;
  if (nrA <= 0) return;
  const int nrows = (nrA < 128) ? nrA : 128;
  const int row0 = meta[M_TR + tb] + half * 128;
  const int e = meta[M_TE + tb];
  const int tid = threadIdx.x, lane = tid & 63, wid = tid >> 6;
  const int wr = wid >> 1, wc = wid & 1;
  const unsigned ldsBase = (unsigned)(unsigned long long)&lds[0];
  constexpr int NT = H_ / BK_;  // 22

  // staging: pass i covers rows (tid>>3)+i*32, col (tid&7)*16 pre-swizzled
  const char* aSrc[4];
  const char* bSrc[4];
  {
    const int r8 = tid >> 3;
    const unsigned colb0 = (unsigned)(tid & 7) * 16u;
#pragma unroll
    for (int i = 0; i < 4; ++i) {
      const int r = r8 + i * 32;
      const unsigned colb = colb0 ^ ((unsigned)(r & 7) << 4);
      const int rc = (r < nrows) ? r : 0;
      aSrc[i] = actb + (size_t)(row0 + rc) * (H_ * 2) + colb;
      const int brow = cb * 128 + r;
      bSrc[i] = w2b + (size_t)e * D_ * (H_ * 2) + (size_t)brow * (H_ * 2) + colb;
    }
  }

  const int l15 = lane & 15, hi = lane >> 4;
  const unsigned swz = (unsigned)(l15 & 7) << 4;
  unsigned aOff[4], bOff[4];
#pragma unroll
  for (int m = 0; m < 4; ++m) {
    const int ra = wr * 64 + m * 16 + l15;
    aOff[m] = (unsigned)(ra * 128) + (((unsigned)hi * 16u) ^ swz);
    const int rb = wc * 64 + m * 16 + l15;
    bOff[m] = 16384u + (unsigned)(rb * 128) + (((unsigned)hi * 16u) ^ swz);
  }

  f32x4 acc[4][4];
#pragma unroll
  for (int m = 0; m < 4; ++m)
#pragma unroll
    for (int n = 0; n < 4; ++n) acc[m][n] = (f32x4){0.f, 0.f, 0.f, 0.f};

  auto STAGE = [&](int t) {
    const size_t kb = (size_t)t * 128;
    const unsigned dst = ldsBase + (unsigned)tid * 16u;
#pragma unroll
    for (int i = 0; i < 4; ++i) {
      gload16(aSrc[i] + kb, dst + (unsigned)i * 4096u);
      gload16(bSrc[i] + kb, dst + 16384u + (unsigned)i * 4096u);
    }
  };

  STAGE(0);
  for (int t = 0; t < NT; ++t) {
    VM0(); SCHED(); SBAR();
#pragma unroll
    for (int ks = 0; ks < 2; ++ks) {
      bf16x8 a[4], b[4];
#pragma unroll
      for (int m = 0; m < 4; ++m) {
        a[m] = *reinterpret_cast<const bf16x8*>(lds + (aOff[m] ^ (unsigned)(ks << 6)));
        b[m] = *reinterpret_cast<const bf16x8*>(lds + (bOff[m] ^ (unsigned)(ks << 6)));
      }
      PRIO1();
#pragma unroll
      for (int m = 0; m < 4; ++m)
#pragma unroll
        for (int n = 0; n < 4; ++n)
          acc[m][n] = __builtin_amdgcn_mfma_f32_16x16x32_bf16(a[m], b[n], acc[m][n], 0, 0, 0);
      PRIO0();
    }
    SCHED(); SBAR();
    if (t + 1 < NT) STAGE(t + 1);
  }

#pragma unroll
  for (int m = 0; m < 4; ++m)
#pragma unroll
    for (int j = 0; j < 4; ++j) {
      const int r = wr * 64 + m * 16 + hi * 4 + j;
      if (r < nrows) {
        const float w = wgt[row0 + r];
        const int token = perm[row0 + r];
        float* yrow = y + (size_t)token * D_ + (size_t)cb * 128 + (size_t)wc * 64;
#pragma unroll
        for (int n = 0; n < 4; ++n)
          unsafeAtomicAdd(&yrow[n * 16 + l15], acc[m][n][j] * w);
      }
    }
}

extern "C" void kernel_launch(void* const* d_in, const int* in_sizes, int n_in,
                              void* d_out, int out_size, void* d_ws, size_t ws_size,
                              hipStream_t stream) {
  const float* x   = (const float*)d_in[0];
  const float* wts = (const float*)d_in[1];
  const int*   idx = (const int*)d_in[2];
  const float* W1  = (const float*)d_in[3];
  const float* W2  = (const float*)d_in[4];
  float* y = (float*)d_out;
  char* ws = (char*)d_ws;

  unsigned short* xb  = (unsigned short*)(ws + XB_OFF);
  unsigned short* w1b = (unsigned short*)(ws + W1B_OFF);
  unsigned short* w2b = (unsigned short*)(ws + W2B_OFF);
  unsigned short* act = (unsigned short*)(ws + ACT_OFF);
  int*   perm = (int*)(ws + PERM_OFF);
  float* wgt  = (float*)(ws + WGT_OFF);
  int*   meta = (int*)(ws + META_B);

  prep_kernel<<<2049, 1024, 0, stream>>>(x, W1, idx, wts, y, xb, w1b, meta, perm, wgt);

  gemm1_kernel<<<CVTB_ + MAXT_ * (H_ / 128), 512, 0, stream>>>(
      (const char*)xb, (const char*)w1b, perm, meta, act, W2, w2b);

  gemm2_kernel<<<MAXT_ * 2 * (D_ / 128), 256, 0, stream>>>(
      (const char*)act, (const char*)w2b, perm, wgt, meta, y);
}

// Round 12
// 1549.427 us; speedup vs baseline: 1.0390x; 1.0137x over previous
//
#include <hip/hip_runtime.h>

#define D_ 2048
#define H_ 1408
#define E_ 16
#define T_ 16384
#define K_ 4
#define TK_ 65536
#define BM_ 256
#define BK_ 64
#define MAXT_ 272
#define CVTB_ 408   // W2-cvt blocks fused into gemm1 launch (51 per XCD)

typedef __attribute__((ext_vector_type(8))) short bf16x8;
typedef __attribute__((ext_vector_type(4))) float f32x4;
typedef __attribute__((ext_vector_type(4))) unsigned short u16x4;

#define M_NT     49
#define M_TE     64
#define M_TR     (64 + MAXT_)
#define M_TN     (64 + 2*MAXT_)

#define XB_OFF   0ULL
#define W1B_OFF  67108864ULL                      // T*D*2
#define W2B_OFF  (W1B_OFF + 188743680ULL)
#define ACT_OFF  (W2B_OFF + 94371840ULL)
#define PERM_OFF (ACT_OFF + 184549376ULL)         // TK*H*2
#define WGT_OFF  (PERM_OFF + 262144ULL)
#define META_B   (WGT_OFF + 262144ULL)

#define SBAR()  __builtin_amdgcn_s_barrier()
#define SCHED() __builtin_amdgcn_sched_barrier(0)
#define VM0()   asm volatile("s_waitcnt vmcnt(0)" ::: "memory")
#define VM6()   asm volatile("s_waitcnt vmcnt(6)" ::: "memory")
#define VM8()   asm volatile("s_waitcnt vmcnt(8)" ::: "memory")
#define PRIO1() __builtin_amdgcn_s_setprio(1)
#define PRIO0() __builtin_amdgcn_s_setprio(0)

static __device__ __forceinline__ unsigned short f2bf(float f) {
  unsigned u = __builtin_bit_cast(unsigned, f);
  u += 0x7fffu + ((u >> 16) & 1u);
  return (unsigned short)(u >> 16);
}

static __device__ __forceinline__ void gload16(const void* g, unsigned ldsOff) {
  __builtin_amdgcn_global_load_lds(
      (const __attribute__((address_space(1))) unsigned int*)(unsigned long long)g,
      (__attribute__((address_space(3))) unsigned int*)(unsigned long long)ldsOff,
      16, 0, 0);
}

// ---------------- prep: zero y + cvt x + cvt W1 (streaming blocks); last block: full routing
__global__ __launch_bounds__(1024) void prep_kernel(
    const float* __restrict__ x, const float* __restrict__ W1,
    const int* __restrict__ idx, const float* __restrict__ wts,
    float* __restrict__ y, unsigned short* __restrict__ xb,
    unsigned short* __restrict__ w1b, int* __restrict__ meta,
    int* __restrict__ perm, float* __restrict__ wgt) {
  const int tid = threadIdx.x;
  if (blockIdx.x == gridDim.x - 1) {
    __shared__ int cnt[E_], cur[E_];
    if (tid < E_) cnt[tid] = 0;
    __syncthreads();
    for (int i = tid; i < TK_; i += 1024) atomicAdd(&cnt[idx[i]], 1);
    __syncthreads();
    if (tid == 0) {
      int off = 0, nt = 0;
      for (int e = 0; e < E_; ++e) {
        cur[e] = off;
        const int c = cnt[e];
        for (int r = 0; r < c; r += BM_) {
          meta[M_TE + nt] = e;
          meta[M_TR + nt] = off + r;
          meta[M_TN + nt] = (c - r < BM_) ? (c - r) : BM_;
          ++nt;
        }
        off += c;
      }
      meta[M_NT] = nt;
    }
    __syncthreads();
    for (int i = tid; i < TK_; i += 1024) {
      const int pos = atomicAdd(&cur[idx[i]], 1);
      perm[pos] = i >> 2;
      wgt[pos] = wts[i];
    }
    return;
  }
  const long long base = ((long long)blockIdx.x * 1024 + tid) * 4;
  const long long stride = (long long)(gridDim.x - 1) * 1024 * 4;
  for (long long i = base; i < (long long)T_ * D_; i += stride)
    *reinterpret_cast<float4*>(y + i) = (float4){0.f, 0.f, 0.f, 0.f};
  for (long long i = base; i < (long long)T_ * D_; i += stride) {
    float4 v = *reinterpret_cast<const float4*>(x + i);
    u16x4 o = { f2bf(v.x), f2bf(v.y), f2bf(v.z), f2bf(v.w) };
    *reinterpret_cast<u16x4*>(xb + i) = o;
  }
  for (long long i = base; i < (long long)E_ * 2 * H_ * D_; i += stride) {
    float4 v = *reinterpret_cast<const float4*>(W1 + i);
    u16x4 o = { f2bf(v.x), f2bf(v.y), f2bf(v.z), f2bf(v.w) };
    *reinterpret_cast<u16x4*>(w1b + i) = o;
  }
}

// ---------------- GEMM1 (+fused W2 cvt): 256 rows x (128 u + 128 g), 4-phase,
// 4 barriers/K-tile, one-phase ds_read-ahead (R10 form, unchanged)
__global__ __launch_bounds__(512, 2) void gemm1_kernel(
    const char* __restrict__ xb, const char* __restrict__ w1b,
    const int* __restrict__ perm, const int* __restrict__ meta,
    unsigned short* __restrict__ act,
    const float* __restrict__ W2, unsigned short* __restrict__ w2b) {
  const int tid = threadIdx.x;
  const int bid0 = (int)blockIdx.x;
  if (bid0 < CVTB_) {
    long long i = ((long long)bid0 * 512 + tid) * 4;
    const long long stride = (long long)CVTB_ * 512 * 4;
    for (; i < (long long)E_ * D_ * H_; i += stride) {
      float4 v = *reinterpret_cast<const float4*>(W2 + i);
      u16x4 o = { f2bf(v.x), f2bf(v.y), f2bf(v.z), f2bf(v.w) };
      *reinterpret_cast<u16x4*>(w2b + i) = o;
    }
    return;
  }
  __shared__ char lds[131072];
  int bid = bid0 - CVTB_;
  bid = (bid & 7) * 374 + (bid >> 3);
  const int tb = bid / 11;
  const int cb = bid - tb * 11;
  if (tb >= meta[M_NT]) return;
  const int e = meta[M_TE + tb];
  const int row0 = meta[M_TR + tb];
  const int nrows = meta[M_TN + tb];
  const int lane = tid & 63, wid = tid >> 6;
  const int wr = wid >> 2, wc = wid & 3;
  const unsigned ldsBase = (unsigned)(unsigned long long)&lds[0];
  constexpr int NT = D_ / BK_;  // 32

  const char* aSrc[4];
  const char* bSrc[4];
  {
    const int r8 = tid >> 3;
    const unsigned colb0 = (unsigned)(tid & 7) * 16u;
#pragma unroll
    for (int i = 0; i < 4; ++i) {
      const int r = r8 + i * 64;
      const unsigned colb = colb0 ^ ((unsigned)(r & 7) << 4);
      const int rc = (r < nrows) ? r : 0;
      aSrc[i] = xb + (size_t)perm[row0 + rc] * 4096 + colb;
      const int w1row = (i < 2) ? (cb * 128 + r) : (H_ + cb * 128 + (r - 128));
      bSrc[i] = w1b + (size_t)e * (2 * H_) * 4096ULL + (size_t)w1row * 4096 + colb;
    }
  }

  const int l15 = lane & 15, hi = lane >> 4;
  const unsigned swz = (unsigned)(l15 & 7) << 4;
  unsigned aOff[8], bOffU[2], bOffG[2];
#pragma unroll
  for (int m = 0; m < 8; ++m) {
    const int row = wr * 128 + m * 16 + l15;
    aOff[m] = (unsigned)(row * 128) + (((unsigned)hi * 16u) ^ swz);
  }
#pragma unroll
  for (int n = 0; n < 2; ++n) {
    const int ru = wc * 32 + n * 16 + l15;
    bOffU[n] = 65536u + (unsigned)(ru * 128) + (((unsigned)hi * 16u) ^ swz);
    const int rg = ru + 128;
    bOffG[n] = 65536u + (unsigned)(rg * 128) + (((unsigned)hi * 16u) ^ swz);
  }

  f32x4 aU[8][2], aG[8][2];
#pragma unroll
  for (int m = 0; m < 8; ++m)
#pragma unroll
    for (int n = 0; n < 2; ++n) {
      aU[m][n] = (f32x4){0.f, 0.f, 0.f, 0.f};
      aG[m][n] = (f32x4){0.f, 0.f, 0.f, 0.f};
    }

  auto STAGE_A = [&](int t, int h) {
    const int tt = (t < NT) ? t : (NT - 1);
    const size_t kb = (size_t)tt * 128;
    const unsigned dst = ldsBase + (unsigned)(t & 1) * 32768u + (unsigned)h * 16384u + (unsigned)tid * 16u;
    gload16(aSrc[h * 2 + 0] + kb, dst);
    gload16(aSrc[h * 2 + 1] + kb, dst + 8192u);
  };
  auto STAGE_B = [&](int t, int h) {
    const int tt = (t < NT) ? t : (NT - 1);
    const size_t kb = (size_t)tt * 128;
    const unsigned dst = ldsBase + 65536u + (unsigned)(t & 1) * 32768u + (unsigned)h * 16384u + (unsigned)tid * 16u;
    gload16(bSrc[h * 2 + 0] + kb, dst);
    gload16(bSrc[h * 2 + 1] + kb, dst + 8192u);
  };

  STAGE_B(0, 0); STAGE_B(0, 1); STAGE_A(0, 0); STAGE_A(0, 1);
  STAGE_B(1, 0); STAGE_B(1, 1); STAGE_A(1, 0);
  VM6(); SCHED(); SBAR();

  bf16x8 aLo[4][2], aHi[4][2], bu[2][2], bg[2][2];
#pragma unroll
  for (int ks = 0; ks < 2; ++ks) {
#pragma unroll
    for (int m = 0; m < 4; ++m)
      aLo[m][ks] = *reinterpret_cast<const bf16x8*>(lds + (aOff[m] ^ (unsigned)(ks << 6)));
#pragma unroll
    for (int n = 0; n < 2; ++n)
      bu[n][ks] = *reinterpret_cast<const bf16x8*>(lds + (bOffU[n] ^ (unsigned)(ks << 6)));
  }

  for (int t = 0; t < NT; ++t) {
    const char* base = lds + (unsigned)(t & 1) * 32768u;
    const char* nbase = lds + (unsigned)((t + 1) & 1) * 32768u;

#pragma unroll
    for (int ks = 0; ks < 2; ++ks)
#pragma unroll
      for (int n = 0; n < 2; ++n)
        bg[n][ks] = *reinterpret_cast<const bf16x8*>(base + (bOffG[n] ^ (unsigned)(ks << 6)));
    STAGE_A(t + 1, 1);
    SCHED();
    PRIO1();
#pragma unroll
    for (int ks = 0; ks < 2; ++ks)
#pragma unroll
      for (int m = 0; m < 4; ++m)
#pragma unroll
        for (int n = 0; n < 2; ++n)
          aU[m][n] = __builtin_amdgcn_mfma_f32_16x16x32_bf16(aLo[m][ks], bu[n][ks], aU[m][n], 0, 0, 0);
    PRIO0(); SCHED(); SBAR();

#pragma unroll
    for (int ks = 0; ks < 2; ++ks)
#pragma unroll
      for (int m = 0; m < 4; ++m)
        aHi[m][ks] = *reinterpret_cast<const bf16x8*>(base + (aOff[4 + m] ^ (unsigned)(ks << 6)));
    STAGE_B(t + 2, 0);
    SCHED();
    PRIO1();
#pragma unroll
    for (int ks = 0; ks < 2; ++ks)
#pragma unroll
      for (int m = 0; m < 4; ++m)
#pragma unroll
        for (int n = 0; n < 2; ++n)
          aG[m][n] = __builtin_amdgcn_mfma_f32_16x16x32_bf16(aLo[m][ks], bg[n][ks], aG[m][n], 0, 0, 0);
    PRIO0(); SCHED(); SBAR();

    STAGE_B(t + 2, 1);
    SCHED();
    PRIO1();
#pragma unroll
    for (int ks = 0; ks < 2; ++ks)
#pragma unroll
      for (int m = 0; m < 4; ++m)
#pragma unroll
        for (int n = 0; n < 2; ++n)
          aU[4 + m][n] = __builtin_amdgcn_mfma_f32_16x16x32_bf16(aHi[m][ks], bu[n][ks], aU[4 + m][n], 0, 0, 0);
    PRIO0(); SCHED(); SBAR();

    STAGE_A(t + 2, 0);
    VM6(); SCHED(); SBAR();
#pragma unroll
    for (int ks = 0; ks < 2; ++ks) {
#pragma unroll
      for (int m = 0; m < 4; ++m)
        aLo[m][ks] = *reinterpret_cast<const bf16x8*>(nbase + (aOff[m] ^ (unsigned)(ks << 6)));
#pragma unroll
      for (int n = 0; n < 2; ++n)
        bu[n][ks] = *reinterpret_cast<const bf16x8*>(nbase + (bOffU[n] ^ (unsigned)(ks << 6)));
    }
    SCHED();
    PRIO1();
#pragma unroll
    for (int ks = 0; ks < 2; ++ks)
#pragma unroll
      for (int m = 0; m < 4; ++m)
#pragma unroll
        for (int n = 0; n < 2; ++n)
          aG[4 + m][n] = __builtin_amdgcn_mfma_f32_16x16x32_bf16(aHi[m][ks], bg[n][ks], aG[4 + m][n], 0, 0, 0);
    PRIO0(); SCHED();
  }

#pragma unroll
  for (int m = 0; m < 8; ++m)
#pragma unroll
    for (int j = 0; j < 4; ++j) {
      const int r = wr * 128 + m * 16 + hi * 4 + j;
      if (r < nrows) {
        const size_t rowBase = (size_t)(row0 + r) * H_ + (size_t)cb * 128 + (size_t)wc * 32;
#pragma unroll
        for (int n = 0; n < 2; ++n) {
          const float u = aU[m][n][j];
          const float g = aG[m][n][j];
          act[rowBase + n * 16 + l15] = f2bf(u * (g / (1.0f + __expf(-g))));
        }
      }
    }
}

// ---------------- GEMM2: 128x128 tile, BK=64, DOUBLE-buffered counted-vmcnt loop
// (R2-proven structure resized). 64KB LDS -> 2 blocks/CU. 256 thr, 4 waves (2x2).
__global__ __launch_bounds__(256, 2) void gemm2_kernel(
    const char* __restrict__ actb, const char* __restrict__ w2b,
    const int* __restrict__ perm, const float* __restrict__ wgt,
    const int* __restrict__ meta, float* __restrict__ y) {
  __shared__ char lds[65536];  // A: buf c @ c*16K; B: 32K + c*16K
  int bid = (int)blockIdx.x;
  bid = (bid & 7) * ((int)gridDim.x >> 3) + (bid >> 3);  // 8704%8==0
  const int st = bid >> 4;     // row subtile (128 rows)
  const int cb = bid & 15;     // 128-col block of D
  const int tb = st >> 1, half = st & 1;
  if (tb >= meta[M_NT]) return;
  const int nrA = meta[M_TN + tb] - half * 128;
  if (nrA <= 0) return;
  const int nrows = (nrA < 128) ? nrA : 128;
  const int row0 = meta[M_TR + tb] + half * 128;
  const int e = meta[M_TE + tb];
  const int tid = threadIdx.x, lane = tid & 63, wid = tid >> 6;
  const int wr = wid >> 1, wc = wid & 1;
  const unsigned ldsBase = (unsigned)(unsigned long long)&lds[0];
  constexpr int NT = H_ / BK_;  // 22

  const char* aSrc[4];
  const char* bSrc[4];
  {
    const int r8 = tid >> 3;
    const unsigned colb0 = (unsigned)(tid & 7) * 16u;
#pragma unroll
    for (int i = 0; i < 4; ++i) {
      const int r = r8 + i * 32;
      const unsigned colb = colb0 ^ ((unsigned)(r & 7) << 4);
      const int rc = (r < nrows) ? r : 0;
      aSrc[i] = actb + (size_t)(row0 + rc) * (H_ * 2) + colb;
      const int brow = cb * 128 + r;
      bSrc[i] = w2b + (size_t)e * D_ * (H_ * 2) + (size_t)brow * (H_ * 2) + colb;
    }
  }

  const int l15 = lane & 15, hi = lane >> 4;
  const unsigned swz = (unsigned)(l15 & 7) << 4;
  unsigned aOff[4], bOff[4];
#pragma unroll
  for (int m = 0; m < 4; ++m) {
    const int ra = wr * 64 + m * 16 + l15;
    aOff[m] = (unsigned)(ra * 128) + (((unsigned)hi * 16u) ^ swz);
    const int rb = wc * 64 + m * 16 + l15;
    bOff[m] = 32768u + (unsigned)(rb * 128) + (((unsigned)hi * 16u) ^ swz);
  }

  f32x4 acc[4][4];
#pragma unroll
  for (int m = 0; m < 4; ++m)
#pragma unroll
    for (int n = 0; n < 4; ++n) acc[m][n] = (f32x4){0.f, 0.f, 0.f, 0.f};

  auto STAGE = [&](int t, int c) {
    const size_t kb = (size_t)t * 128;
    const unsigned dst = ldsBase + (unsigned)c * 16384u + (unsigned)tid * 16u;
#pragma unroll
    for (int i = 0; i < 4; ++i) {
      gload16(aSrc[i] + kb, dst + (unsigned)i * 4096u);
      gload16(bSrc[i] + kb, dst + 32768u + (unsigned)i * 4096u);
    }
  };

  STAGE(0, 0);
  for (int t = 0; t < NT; ++t) {
    if (t + 1 < NT) {
      STAGE(t + 1, (t + 1) & 1);
      VM8();
    } else {
      VM0();
    }
    SCHED(); SBAR();
    const char* abase = lds + (unsigned)(t & 1) * 16384u;
#pragma unroll
    for (int ks = 0; ks < 2; ++ks) {
      bf16x8 a[4], b[4];
#pragma unroll
      for (int m = 0; m < 4; ++m) {
        a[m] = *reinterpret_cast<const bf16x8*>(abase + (aOff[m] ^ (unsigned)(ks << 6)));
        b[m] = *reinterpret_cast<const bf16x8*>(abase + (bOff[m] ^ (unsigned)(ks << 6)));
      }
      PRIO1();
#pragma unroll
      for (int m = 0; m < 4; ++m)
#pragma unroll
        for (int n = 0; n < 4; ++n)
          acc[m][n] = __builtin_amdgcn_mfma_f32_16x16x32_bf16(a[m], b[n], acc[m][n], 0, 0, 0);
      PRIO0();
    }
    SCHED(); SBAR();
  }

#pragma unroll
  for (int m = 0; m < 4; ++m)
#pragma unroll
    for (int j = 0; j < 4; ++j) {
      const int r = wr * 64 + m * 16 + hi * 4 + j;
      if (r < nrows) {
        const float w = wgt[row0 + r];
        const int token = perm[row0 + r];
        float* yrow = y + (size_t)token * D_ + (size_t)cb * 128 + (size_t)wc * 64;
#pragma unroll
        for (int n = 0; n < 4; ++n)
          unsafeAtomicAdd(&yrow[n * 16 + l15], acc[m][n][j] * w);
      }
    }
}

extern "C" void kernel_launch(void* const* d_in, const int* in_sizes, int n_in,
                              void* d_out, int out_size, void* d_ws, size_t ws_size,
                              hipStream_t stream) {
  const float* x   = (const float*)d_in[0];
  const float* wts = (const float*)d_in[1];
  const int*   idx = (const int*)d_in[2];
  const float* W1  = (const float*)d_in[3];
  const float* W2  = (const float*)d_in[4];
  float* y = (float*)d_out;
  char* ws = (char*)d_ws;

  unsigned short* xb  = (unsigned short*)(ws + XB_OFF);
  unsigned short* w1b = (unsigned short*)(ws + W1B_OFF);
  unsigned short* w2b = (unsigned short*)(ws + W2B_OFF);
  unsigned short* act = (unsigned short*)(ws + ACT_OFF);
  int*   perm = (int*)(ws + PERM_OFF);
  float* wgt  = (float*)(ws + WGT_OFF);
  int*   meta = (int*)(ws + META_B);

  prep_kernel<<<2049, 1024, 0, stream>>>(x, W1, idx, wts, y, xb, w1b, meta, perm, wgt);

  gemm1_kernel<<<CVTB_ + MAXT_ * (H_ / 128), 512, 0, stream>>>(
      (const char*)xb, (const char*)w1b, perm, meta, act, W2, w2b);

  gemm2_kernel<<<MAXT_ * 2 * (D_ / 128), 256, 0, stream>>>(
      (const char*)act, (const char*)w2b, perm, wgt, meta, y);
}

// Round 13
// 1541.626 us; speedup vs baseline: 1.0443x; 1.0051x over previous
//
#include <hip/hip_runtime.h>

#define D_ 2048
#define H_ 1408
#define E_ 16
#define T_ 16384
#define K_ 4
#define TK_ 65536
#define BM_ 256
#define BK_ 64
#define MAXT_ 272
#define CVTB_ 408   // W2-cvt blocks fused into gemm1 launch (51 per XCD)

typedef __attribute__((ext_vector_type(8))) short bf16x8;
typedef __attribute__((ext_vector_type(4))) float f32x4;
typedef __attribute__((ext_vector_type(4))) unsigned short u16x4;

#define M_NT     49
#define M_TE     64
#define M_TR     (64 + MAXT_)
#define M_TN     (64 + 2*MAXT_)

#define XB_OFF   0ULL
#define W1B_OFF  67108864ULL                      // T*D*2
#define W2B_OFF  (W1B_OFF + 188743680ULL)
#define ACT_OFF  (W2B_OFF + 94371840ULL)
#define PERM_OFF (ACT_OFF + 184549376ULL)         // TK*H*2
#define WGT_OFF  (PERM_OFF + 262144ULL)
#define META_B   (WGT_OFF + 262144ULL)

#define SBAR()  __builtin_amdgcn_s_barrier()
#define SCHED() __builtin_amdgcn_sched_barrier(0)
#define VM0()   asm volatile("s_waitcnt vmcnt(0)" ::: "memory")
#define VM6()   asm volatile("s_waitcnt vmcnt(6)" ::: "memory")
#define VM8()   asm volatile("s_waitcnt vmcnt(8)" ::: "memory")
#define PRIO1() __builtin_amdgcn_s_setprio(1)
#define PRIO0() __builtin_amdgcn_s_setprio(0)

static __device__ __forceinline__ unsigned short f2bf(float f) {
  unsigned u = __builtin_bit_cast(unsigned, f);
  u += 0x7fffu + ((u >> 16) & 1u);
  return (unsigned short)(u >> 16);
}

static __device__ __forceinline__ void gload16(const void* g, unsigned ldsOff) {
  __builtin_amdgcn_global_load_lds(
      (const __attribute__((address_space(1))) unsigned int*)(unsigned long long)g,
      (__attribute__((address_space(3))) unsigned int*)(unsigned long long)ldsOff,
      16, 0, 0);
}

// ---------------- prep: zero y + cvt x + cvt W1 (streaming blocks); last block: full routing
__global__ __launch_bounds__(1024) void prep_kernel(
    const float* __restrict__ x, const float* __restrict__ W1,
    const int* __restrict__ idx, const float* __restrict__ wts,
    float* __restrict__ y, unsigned short* __restrict__ xb,
    unsigned short* __restrict__ w1b, int* __restrict__ meta,
    int* __restrict__ perm, float* __restrict__ wgt) {
  const int tid = threadIdx.x;
  if (blockIdx.x == gridDim.x - 1) {
    __shared__ int cnt[E_], cur[E_];
    if (tid < E_) cnt[tid] = 0;
    __syncthreads();
    for (int i = tid; i < TK_; i += 1024) atomicAdd(&cnt[idx[i]], 1);
    __syncthreads();
    if (tid == 0) {
      int off = 0, nt = 0;
      for (int e = 0; e < E_; ++e) {
        cur[e] = off;
        const int c = cnt[e];
        for (int r = 0; r < c; r += BM_) {
          meta[M_TE + nt] = e;
          meta[M_TR + nt] = off + r;
          meta[M_TN + nt] = (c - r < BM_) ? (c - r) : BM_;
          ++nt;
        }
        off += c;
      }
      meta[M_NT] = nt;
    }
    __syncthreads();
    for (int i = tid; i < TK_; i += 1024) {
      const int pos = atomicAdd(&cur[idx[i]], 1);
      perm[pos] = i >> 2;
      wgt[pos] = wts[i];
    }
    return;
  }
  const long long base = ((long long)blockIdx.x * 1024 + tid) * 4;
  const long long stride = (long long)(gridDim.x - 1) * 1024 * 4;
  for (long long i = base; i < (long long)T_ * D_; i += stride)
    *reinterpret_cast<float4*>(y + i) = (float4){0.f, 0.f, 0.f, 0.f};
  for (long long i = base; i < (long long)T_ * D_; i += stride) {
    float4 v = *reinterpret_cast<const float4*>(x + i);
    u16x4 o = { f2bf(v.x), f2bf(v.y), f2bf(v.z), f2bf(v.w) };
    *reinterpret_cast<u16x4*>(xb + i) = o;
  }
  for (long long i = base; i < (long long)E_ * 2 * H_ * D_; i += stride) {
    float4 v = *reinterpret_cast<const float4*>(W1 + i);
    u16x4 o = { f2bf(v.x), f2bf(v.y), f2bf(v.z), f2bf(v.w) };
    *reinterpret_cast<u16x4*>(w1b + i) = o;
  }
}

// ---------------- GEMM1 (+fused W2 cvt): 256 rows x (128 u + 128 g), 4-phase,
// 4 barriers/K-tile, one-phase ds_read-ahead. R13: tb-fastest block order
// (17 consumers of each W1 panel are consecutive -> panel stays L2-resident).
__global__ __launch_bounds__(512, 2) void gemm1_kernel(
    const char* __restrict__ xb, const char* __restrict__ w1b,
    const int* __restrict__ perm, const int* __restrict__ meta,
    unsigned short* __restrict__ act,
    const float* __restrict__ W2, unsigned short* __restrict__ w2b) {
  const int tid = threadIdx.x;
  const int bid0 = (int)blockIdx.x;
  if (bid0 < CVTB_) {
    long long i = ((long long)bid0 * 512 + tid) * 4;
    const long long stride = (long long)CVTB_ * 512 * 4;
    for (; i < (long long)E_ * D_ * H_; i += stride) {
      float4 v = *reinterpret_cast<const float4*>(W2 + i);
      u16x4 o = { f2bf(v.x), f2bf(v.y), f2bf(v.z), f2bf(v.w) };
      *reinterpret_cast<u16x4*>(w2b + i) = o;
    }
    return;
  }
  __shared__ char lds[131072];
  int bid = bid0 - CVTB_;
  bid = (bid & 7) * 374 + (bid >> 3);  // XCD-chunked over 2992 (2992/8=374)
  const int cb = bid / MAXT_;          // tb-fastest within chunk -> W1-panel L2 reuse
  const int tb = bid - cb * MAXT_;
  if (tb >= meta[M_NT]) return;
  const int e = meta[M_TE + tb];
  const int row0 = meta[M_TR + tb];
  const int nrows = meta[M_TN + tb];
  const int lane = tid & 63, wid = tid >> 6;
  const int wr = wid >> 2, wc = wid & 3;
  const unsigned ldsBase = (unsigned)(unsigned long long)&lds[0];
  constexpr int NT = D_ / BK_;  // 32

  const char* aSrc[4];
  const char* bSrc[4];
  {
    const int r8 = tid >> 3;
    const unsigned colb0 = (unsigned)(tid & 7) * 16u;
#pragma unroll
    for (int i = 0; i < 4; ++i) {
      const int r = r8 + i * 64;
      const unsigned colb = colb0 ^ ((unsigned)(r & 7) << 4);
      const int rc = (r < nrows) ? r : 0;
      aSrc[i] = xb + (size_t)perm[row0 + rc] * 4096 + colb;
      const int w1row = (i < 2) ? (cb * 128 + r) : (H_ + cb * 128 + (r - 128));
      bSrc[i] = w1b + (size_t)e * (2 * H_) * 4096ULL + (size_t)w1row * 4096 + colb;
    }
  }

  const int l15 = lane & 15, hi = lane >> 4;
  const unsigned swz = (unsigned)(l15 & 7) << 4;
  unsigned aOff[8], bOffU[2], bOffG[2];
#pragma unroll
  for (int m = 0; m < 8; ++m) {
    const int row = wr * 128 + m * 16 + l15;
    aOff[m] = (unsigned)(row * 128) + (((unsigned)hi * 16u) ^ swz);
  }
#pragma unroll
  for (int n = 0; n < 2; ++n) {
    const int ru = wc * 32 + n * 16 + l15;
    bOffU[n] = 65536u + (unsigned)(ru * 128) + (((unsigned)hi * 16u) ^ swz);
    const int rg = ru + 128;
    bOffG[n] = 65536u + (unsigned)(rg * 128) + (((unsigned)hi * 16u) ^ swz);
  }

  f32x4 aU[8][2], aG[8][2];
#pragma unroll
  for (int m = 0; m < 8; ++m)
#pragma unroll
    for (int n = 0; n < 2; ++n) {
      aU[m][n] = (f32x4){0.f, 0.f, 0.f, 0.f};
      aG[m][n] = (f32x4){0.f, 0.f, 0.f, 0.f};
    }

  auto STAGE_A = [&](int t, int h) {
    const int tt = (t < NT) ? t : (NT - 1);
    const size_t kb = (size_t)tt * 128;
    const unsigned dst = ldsBase + (unsigned)(t & 1) * 32768u + (unsigned)h * 16384u + (unsigned)tid * 16u;
    gload16(aSrc[h * 2 + 0] + kb, dst);
    gload16(aSrc[h * 2 + 1] + kb, dst + 8192u);
  };
  auto STAGE_B = [&](int t, int h) {
    const int tt = (t < NT) ? t : (NT - 1);
    const size_t kb = (size_t)tt * 128;
    const unsigned dst = ldsBase + 65536u + (unsigned)(t & 1) * 32768u + (unsigned)h * 16384u + (unsigned)tid * 16u;
    gload16(bSrc[h * 2 + 0] + kb, dst);
    gload16(bSrc[h * 2 + 1] + kb, dst + 8192u);
  };

  STAGE_B(0, 0); STAGE_B(0, 1); STAGE_A(0, 0); STAGE_A(0, 1);
  STAGE_B(1, 0); STAGE_B(1, 1); STAGE_A(1, 0);
  VM6(); SCHED(); SBAR();

  bf16x8 aLo[4][2], aHi[4][2], bu[2][2], bg[2][2];
#pragma unroll
  for (int ks = 0; ks < 2; ++ks) {
#pragma unroll
    for (int m = 0; m < 4; ++m)
      aLo[m][ks] = *reinterpret_cast<const bf16x8*>(lds + (aOff[m] ^ (unsigned)(ks << 6)));
#pragma unroll
    for (int n = 0; n < 2; ++n)
      bu[n][ks] = *reinterpret_cast<const bf16x8*>(lds + (bOffU[n] ^ (unsigned)(ks << 6)));
  }

  for (int t = 0; t < NT; ++t) {
    const char* base = lds + (unsigned)(t & 1) * 32768u;
    const char* nbase = lds + (unsigned)((t + 1) & 1) * 32768u;

#pragma unroll
    for (int ks = 0; ks < 2; ++ks)
#pragma unroll
      for (int n = 0; n < 2; ++n)
        bg[n][ks] = *reinterpret_cast<const bf16x8*>(base + (bOffG[n] ^ (unsigned)(ks << 6)));
    STAGE_A(t + 1, 1);
    SCHED();
    PRIO1();
#pragma unroll
    for (int ks = 0; ks < 2; ++ks)
#pragma unroll
      for (int m = 0; m < 4; ++m)
#pragma unroll
        for (int n = 0; n < 2; ++n)
          aU[m][n] = __builtin_amdgcn_mfma_f32_16x16x32_bf16(aLo[m][ks], bu[n][ks], aU[m][n], 0, 0, 0);
    PRIO0(); SCHED(); SBAR();

#pragma unroll
    for (int ks = 0; ks < 2; ++ks)
#pragma unroll
      for (int m = 0; m < 4; ++m)
        aHi[m][ks] = *reinterpret_cast<const bf16x8*>(base + (aOff[4 + m] ^ (unsigned)(ks << 6)));
    STAGE_B(t + 2, 0);
    SCHED();
    PRIO1();
#pragma unroll
    for (int ks = 0; ks < 2; ++ks)
#pragma unroll
      for (int m = 0; m < 4; ++m)
#pragma unroll
        for (int n = 0; n < 2; ++n)
          aG[m][n] = __builtin_amdgcn_mfma_f32_16x16x32_bf16(aLo[m][ks], bg[n][ks], aG[m][n], 0, 0, 0);
    PRIO0(); SCHED(); SBAR();

    STAGE_B(t + 2, 1);
    SCHED();
    PRIO1();
#pragma unroll
    for (int ks = 0; ks < 2; ++ks)
#pragma unroll
      for (int m = 0; m < 4; ++m)
#pragma unroll
        for (int n = 0; n < 2; ++n)
          aU[4 + m][n] = __builtin_amdgcn_mfma_f32_16x16x32_bf16(aHi[m][ks], bu[n][ks], aU[4 + m][n], 0, 0, 0);
    PRIO0(); SCHED(); SBAR();

    STAGE_A(t + 2, 0);
    VM6(); SCHED(); SBAR();
#pragma unroll
    for (int ks = 0; ks < 2; ++ks) {
#pragma unroll
      for (int m = 0; m < 4; ++m)
        aLo[m][ks] = *reinterpret_cast<const bf16x8*>(nbase + (aOff[m] ^ (unsigned)(ks << 6)));
#pragma unroll
      for (int n = 0; n < 2; ++n)
        bu[n][ks] = *reinterpret_cast<const bf16x8*>(nbase + (bOffU[n] ^ (unsigned)(ks << 6)));
    }
    SCHED();
    PRIO1();
#pragma unroll
    for (int ks = 0; ks < 2; ++ks)
#pragma unroll
      for (int m = 0; m < 4; ++m)
#pragma unroll
        for (int n = 0; n < 2; ++n)
          aG[4 + m][n] = __builtin_amdgcn_mfma_f32_16x16x32_bf16(aHi[m][ks], bg[n][ks], aG[4 + m][n], 0, 0, 0);
    PRIO0(); SCHED();
  }

#pragma unroll
  for (int m = 0; m < 8; ++m)
#pragma unroll
    for (int j = 0; j < 4; ++j) {
      const int r = wr * 128 + m * 16 + hi * 4 + j;
      if (r < nrows) {
        const size_t rowBase = (size_t)(row0 + r) * H_ + (size_t)cb * 128 + (size_t)wc * 32;
#pragma unroll
        for (int n = 0; n < 2; ++n) {
          const float u = aU[m][n][j];
          const float g = aG[m][n][j];
          act[rowBase + n * 16 + l15] = f2bf(u * (g / (1.0f + __expf(-g))));
        }
      }
    }
}

// ---------------- GEMM2: 128x128 tile, BK=64, double-buffered counted-vmcnt (R12 form, unchanged)
__global__ __launch_bounds__(256, 2) void gemm2_kernel(
    const char* __restrict__ actb, const char* __restrict__ w2b,
    const int* __restrict__ perm, const float* __restrict__ wgt,
    const int* __restrict__ meta, float* __restrict__ y) {
  __shared__ char lds[65536];  // A: buf c @ c*16K; B: 32K + c*16K
  int bid = (int)blockIdx.x;
  bid = (bid & 7) * ((int)gridDim.x >> 3) + (bid >> 3);  // 8704%8==0
  const int st = bid >> 4;     // row subtile (128 rows)
  const int cb = bid & 15;     // 128-col block of D
  const int tb = st >> 1, half = st & 1;
  if (tb >= meta[M_NT]) return;
  const int nrA = meta[M_TN + tb] - half * 128;
  if (nrA <= 0) return;
  const int nrows = (nrA < 128) ? nrA : 128;
  const int row0 = meta[M_TR + tb] + half * 128;
  const int e = meta[M_TE + tb];
  const int tid = threadIdx.x, lane = tid & 63, wid = tid >> 6;
  const int wr = wid >> 1, wc = wid & 1;
  const unsigned ldsBase = (unsigned)(unsigned long long)&lds[0];
  constexpr int NT = H_ / BK_;  // 22

  const char* aSrc[4];
  const char* bSrc[4];
  {
    const int r8 = tid >> 3;
    const unsigned colb0 = (unsigned)(tid & 7) * 16u;
#pragma unroll
    for (int i = 0; i < 4; ++i) {
      const int r = r8 + i * 32;
      const unsigned colb = colb0 ^ ((unsigned)(r & 7) << 4);
      const int rc = (r < nrows) ? r : 0;
      aSrc[i] = actb + (size_t)(row0 + rc) * (H_ * 2) + colb;
      const int brow = cb * 128 + r;
      bSrc[i] = w2b + (size_t)e * D_ * (H_ * 2) + (size_t)brow * (H_ * 2) + colb;
    }
  }

  const int l15 = lane & 15, hi = lane >> 4;
  const unsigned swz = (unsigned)(l15 & 7) << 4;
  unsigned aOff[4], bOff[4];
#pragma unroll
  for (int m = 0; m < 4; ++m) {
    const int ra = wr * 64 + m * 16 + l15;
    aOff[m] = (unsigned)(ra * 128) + (((unsigned)hi * 16u) ^ swz);
    const int rb = wc * 64 + m * 16 + l15;
    bOff[m] = 32768u + (unsigned)(rb * 128) + (((unsigned)hi * 16u) ^ swz);
  }

  f32x4 acc[4][4];
#pragma unroll
  for (int m = 0; m < 4; ++m)
#pragma unroll
    for (int n = 0; n < 4; ++n) acc[m][n] = (f32x4){0.f, 0.f, 0.f, 0.f};

  auto STAGE = [&](int t, int c) {
    const size_t kb = (size_t)t * 128;
    const unsigned dst = ldsBase + (unsigned)c * 16384u + (unsigned)tid * 16u;
#pragma unroll
    for (int i = 0; i < 4; ++i) {
      gload16(aSrc[i] + kb, dst + (unsigned)i * 4096u);
      gload16(bSrc[i] + kb, dst + 32768u + (unsigned)i * 4096u);
    }
  };

  STAGE(0, 0);
  for (int t = 0; t < NT; ++t) {
    if (t + 1 < NT) {
      STAGE(t + 1, (t + 1) & 1);
      VM8();
    } else {
      VM0();
    }
    SCHED(); SBAR();
    const char* abase = lds + (unsigned)(t & 1) * 16384u;
#pragma unroll
    for (int ks = 0; ks < 2; ++ks) {
      bf16x8 a[4], b[4];
#pragma unroll
      for (int m = 0; m < 4; ++m) {
        a[m] = *reinterpret_cast<const bf16x8*>(abase + (aOff[m] ^ (unsigned)(ks << 6)));
        b[m] = *reinterpret_cast<const bf16x8*>(abase + (bOff[m] ^ (unsigned)(ks << 6)));
      }
      PRIO1();
#pragma unroll
      for (int m = 0; m < 4; ++m)
#pragma unroll
        for (int n = 0; n < 4; ++n)
          acc[m][n] = __builtin_amdgcn_mfma_f32_16x16x32_bf16(a[m], b[n], acc[m][n], 0, 0, 0);
      PRIO0();
    }
    SCHED(); SBAR();
  }

#pragma unroll
  for (int m = 0; m < 4; ++m)
#pragma unroll
    for (int j = 0; j < 4; ++j) {
      const int r = wr * 64 + m * 16 + hi * 4 + j;
      if (r < nrows) {
        const float w = wgt[row0 + r];
        const int token = perm[row0 + r];
        float* yrow = y + (size_t)token * D_ + (size_t)cb * 128 + (size_t)wc * 64;
#pragma unroll
        for (int n = 0; n < 4; ++n)
          unsafeAtomicAdd(&yrow[n * 16 + l15], acc[m][n][j] * w);
      }
    }
}

extern "C" void kernel_launch(void* const* d_in, const int* in_sizes, int n_in,
                              void* d_out, int out_size, void* d_ws, size_t ws_size,
                              hipStream_t stream) {
  const float* x   = (const float*)d_in[0];
  const float* wts = (const float*)d_in[1];
  const int*   idx = (const int*)d_in[2];
  const float* W1  = (const float*)d_in[3];
  const float* W2  = (const float*)d_in[4];
  float* y = (float*)d_out;
  char* ws = (char*)d_ws;

  unsigned short* xb  = (unsigned short*)(ws + XB_OFF);
  unsigned short* w1b = (unsigned short*)(ws + W1B_OFF);
  unsigned short* w2b = (unsigned short*)(ws + W2B_OFF);
  unsigned short* act = (unsigned short*)(ws + ACT_OFF);
  int*   perm = (int*)(ws + PERM_OFF);
  float* wgt  = (float*)(ws + WGT_OFF);
  int*   meta = (int*)(ws + META_B);

  prep_kernel<<<2049, 1024, 0, stream>>>(x, W1, idx, wts, y, xb, w1b, meta, perm, wgt);

  gemm1_kernel<<<CVTB_ + MAXT_ * (H_ / 128), 512, 0, stream>>>(
      (const char*)xb, (const char*)w1b, perm, meta, act, W2, w2b);

  gemm2_kernel<<<MAXT_ * 2 * (D_ / 128), 256, 0, stream>>>(
      (const char*)act, (const char*)w2b, perm, wgt, meta, y);
}

// Round 14
// 1480.290 us; speedup vs baseline: 1.0876x; 1.0414x over previous
//
#include <hip/hip_runtime.h>

#define D_ 2048
#define H_ 1408
#define E_ 16
#define T_ 16384
#define K_ 4
#define TK_ 65536
#define BM_ 256
#define BK_ 64
#define MAXT_ 272
#define CVTB_ 408   // W2-cvt blocks fused into gemm1 launch (51 per XCD)

typedef __attribute__((ext_vector_type(8))) short bf16x8;
typedef __attribute__((ext_vector_type(4))) float f32x4;
typedef __attribute__((ext_vector_type(4))) unsigned short u16x4;

#define M_NT     49
#define M_TE     64
#define M_TR     (64 + MAXT_)
#define M_TN     (64 + 2*MAXT_)

#define XB_OFF   0ULL
#define W1B_OFF  67108864ULL                      // T*D*2
#define W2B_OFF  (W1B_OFF + 188743680ULL)
#define ACT_OFF  (W2B_OFF + 94371840ULL)
#define PERM_OFF (ACT_OFF + 184549376ULL)         // TK*H*2
#define WGT_OFF  (PERM_OFF + 262144ULL)
#define META_B   (WGT_OFF + 262144ULL)

#define SBAR()  __builtin_amdgcn_s_barrier()
#define SCHED() __builtin_amdgcn_sched_barrier(0)
#define VM0()   asm volatile("s_waitcnt vmcnt(0)" ::: "memory")
#define VM6()   asm volatile("s_waitcnt vmcnt(6)" ::: "memory")
#define VM8()   asm volatile("s_waitcnt vmcnt(8)" ::: "memory")
#define PRIO1() __builtin_amdgcn_s_setprio(1)
#define PRIO0() __builtin_amdgcn_s_setprio(0)

static __device__ __forceinline__ unsigned short f2bf(float f) {
  unsigned u = __builtin_bit_cast(unsigned, f);
  u += 0x7fffu + ((u >> 16) & 1u);
  return (unsigned short)(u >> 16);
}

static __device__ __forceinline__ void gload16(const void* g, unsigned ldsOff) {
  __builtin_amdgcn_global_load_lds(
      (const __attribute__((address_space(1))) unsigned int*)(unsigned long long)g,
      (__attribute__((address_space(3))) unsigned int*)(unsigned long long)ldsOff,
      16, 0, 0);
}

// ---------------- prep: zero y + cvt x + cvt W1 (streaming blocks); last block:
// routing with per-token (t,e) DEDUPE — duplicates merged with summed weights
// (matches reference cw = sum_k w_k [idx_k==e]; removes ~9% of GEMM rows).
__global__ __launch_bounds__(1024) void prep_kernel(
    const float* __restrict__ x, const float* __restrict__ W1,
    const int* __restrict__ idx, const float* __restrict__ wts,
    float* __restrict__ y, unsigned short* __restrict__ xb,
    unsigned short* __restrict__ w1b, int* __restrict__ meta,
    int* __restrict__ perm, float* __restrict__ wgt) {
  const int tid = threadIdx.x;
  if (blockIdx.x == gridDim.x - 1) {
    __shared__ int cnt[E_], cur[E_];
    if (tid < E_) cnt[tid] = 0;
    __syncthreads();
    for (int t = tid; t < T_; t += 1024) {
      int es[4]; int n = 0;
#pragma unroll
      for (int k = 0; k < 4; ++k) {
        const int e = idx[t * 4 + k];
        bool found = false;
        for (int j = 0; j < n; ++j) found |= (es[j] == e);
        if (!found) es[n++] = e;
      }
      for (int j = 0; j < n; ++j) atomicAdd(&cnt[es[j]], 1);
    }
    __syncthreads();
    if (tid == 0) {
      int off = 0, nt = 0;
      for (int e = 0; e < E_; ++e) {
        cur[e] = off;
        const int c = cnt[e];
        for (int r = 0; r < c; r += BM_) {
          meta[M_TE + nt] = e;
          meta[M_TR + nt] = off + r;
          meta[M_TN + nt] = (c - r < BM_) ? (c - r) : BM_;
          ++nt;
        }
        off += c;
      }
      meta[M_NT] = nt;
    }
    __syncthreads();
    for (int t = tid; t < T_; t += 1024) {
      int es[4]; float ws[4]; int n = 0;
#pragma unroll
      for (int k = 0; k < 4; ++k) {
        const int e = idx[t * 4 + k];
        const float w = wts[t * 4 + k];
        bool found = false;
        for (int j = 0; j < n; ++j)
          if (es[j] == e) { ws[j] += w; found = true; }
        if (!found) { es[n] = e; ws[n] = w; ++n; }
      }
      for (int j = 0; j < n; ++j) {
        const int pos = atomicAdd(&cur[es[j]], 1);
        perm[pos] = t;
        wgt[pos] = ws[j];
      }
    }
    return;
  }
  const long long base = ((long long)blockIdx.x * 1024 + tid) * 4;
  const long long stride = (long long)(gridDim.x - 1) * 1024 * 4;
  for (long long i = base; i < (long long)T_ * D_; i += stride)
    *reinterpret_cast<float4*>(y + i) = (float4){0.f, 0.f, 0.f, 0.f};
  for (long long i = base; i < (long long)T_ * D_; i += stride) {
    float4 v = *reinterpret_cast<const float4*>(x + i);
    u16x4 o = { f2bf(v.x), f2bf(v.y), f2bf(v.z), f2bf(v.w) };
    *reinterpret_cast<u16x4*>(xb + i) = o;
  }
  for (long long i = base; i < (long long)E_ * 2 * H_ * D_; i += stride) {
    float4 v = *reinterpret_cast<const float4*>(W1 + i);
    u16x4 o = { f2bf(v.x), f2bf(v.y), f2bf(v.z), f2bf(v.w) };
    *reinterpret_cast<u16x4*>(w1b + i) = o;
  }
}

// ---------------- GEMM1 (+fused W2 cvt): 256 rows x (128 u + 128 g), 4-phase,
// 4 barriers/K-tile, one-phase ds_read-ahead, tb-fastest order (R13 form, unchanged)
__global__ __launch_bounds__(512, 2) void gemm1_kernel(
    const char* __restrict__ xb, const char* __restrict__ w1b,
    const int* __restrict__ perm, const int* __restrict__ meta,
    unsigned short* __restrict__ act,
    const float* __restrict__ W2, unsigned short* __restrict__ w2b) {
  const int tid = threadIdx.x;
  const int bid0 = (int)blockIdx.x;
  if (bid0 < CVTB_) {
    long long i = ((long long)bid0 * 512 + tid) * 4;
    const long long stride = (long long)CVTB_ * 512 * 4;
    for (; i < (long long)E_ * D_ * H_; i += stride) {
      float4 v = *reinterpret_cast<const float4*>(W2 + i);
      u16x4 o = { f2bf(v.x), f2bf(v.y), f2bf(v.z), f2bf(v.w) };
      *reinterpret_cast<u16x4*>(w2b + i) = o;
    }
    return;
  }
  __shared__ char lds[131072];
  int bid = bid0 - CVTB_;
  bid = (bid & 7) * 374 + (bid >> 3);  // XCD-chunked over 2992 (2992/8=374)
  const int cb = bid / MAXT_;          // tb-fastest within chunk -> W1-panel L2 reuse
  const int tb = bid - cb * MAXT_;
  if (tb >= meta[M_NT]) return;
  const int e = meta[M_TE + tb];
  const int row0 = meta[M_TR + tb];
  const int nrows = meta[M_TN + tb];
  const int lane = tid & 63, wid = tid >> 6;
  const int wr = wid >> 2, wc = wid & 3;
  const unsigned ldsBase = (unsigned)(unsigned long long)&lds[0];
  constexpr int NT = D_ / BK_;  // 32

  const char* aSrc[4];
  const char* bSrc[4];
  {
    const int r8 = tid >> 3;
    const unsigned colb0 = (unsigned)(tid & 7) * 16u;
#pragma unroll
    for (int i = 0; i < 4; ++i) {
      const int r = r8 + i * 64;
      const unsigned colb = colb0 ^ ((unsigned)(r & 7) << 4);
      const int rc = (r < nrows) ? r : 0;
      aSrc[i] = xb + (size_t)perm[row0 + rc] * 4096 + colb;
      const int w1row = (i < 2) ? (cb * 128 + r) : (H_ + cb * 128 + (r - 128));
      bSrc[i] = w1b + (size_t)e * (2 * H_) * 4096ULL + (size_t)w1row * 4096 + colb;
    }
  }

  const int l15 = lane & 15, hi = lane >> 4;
  const unsigned swz = (unsigned)(l15 & 7) << 4;
  unsigned aOff[8], bOffU[2], bOffG[2];
#pragma unroll
  for (int m = 0; m < 8; ++m) {
    const int row = wr * 128 + m * 16 + l15;
    aOff[m] = (unsigned)(row * 128) + (((unsigned)hi * 16u) ^ swz);
  }
#pragma unroll
  for (int n = 0; n < 2; ++n) {
    const int ru = wc * 32 + n * 16 + l15;
    bOffU[n] = 65536u + (unsigned)(ru * 128) + (((unsigned)hi * 16u) ^ swz);
    const int rg = ru + 128;
    bOffG[n] = 65536u + (unsigned)(rg * 128) + (((unsigned)hi * 16u) ^ swz);
  }

  f32x4 aU[8][2], aG[8][2];
#pragma unroll
  for (int m = 0; m < 8; ++m)
#pragma unroll
    for (int n = 0; n < 2; ++n) {
      aU[m][n] = (f32x4){0.f, 0.f, 0.f, 0.f};
      aG[m][n] = (f32x4){0.f, 0.f, 0.f, 0.f};
    }

  auto STAGE_A = [&](int t, int h) {
    const int tt = (t < NT) ? t : (NT - 1);
    const size_t kb = (size_t)tt * 128;
    const unsigned dst = ldsBase + (unsigned)(t & 1) * 32768u + (unsigned)h * 16384u + (unsigned)tid * 16u;
    gload16(aSrc[h * 2 + 0] + kb, dst);
    gload16(aSrc[h * 2 + 1] + kb, dst + 8192u);
  };
  auto STAGE_B = [&](int t, int h) {
    const int tt = (t < NT) ? t : (NT - 1);
    const size_t kb = (size_t)tt * 128;
    const unsigned dst = ldsBase + 65536u + (unsigned)(t & 1) * 32768u + (unsigned)h * 16384u + (unsigned)tid * 16u;
    gload16(bSrc[h * 2 + 0] + kb, dst);
    gload16(bSrc[h * 2 + 1] + kb, dst + 8192u);
  };

  STAGE_B(0, 0); STAGE_B(0, 1); STAGE_A(0, 0); STAGE_A(0, 1);
  STAGE_B(1, 0); STAGE_B(1, 1); STAGE_A(1, 0);
  VM6(); SCHED(); SBAR();

  bf16x8 aLo[4][2], aHi[4][2], bu[2][2], bg[2][2];
#pragma unroll
  for (int ks = 0; ks < 2; ++ks) {
#pragma unroll
    for (int m = 0; m < 4; ++m)
      aLo[m][ks] = *reinterpret_cast<const bf16x8*>(lds + (aOff[m] ^ (unsigned)(ks << 6)));
#pragma unroll
    for (int n = 0; n < 2; ++n)
      bu[n][ks] = *reinterpret_cast<const bf16x8*>(lds + (bOffU[n] ^ (unsigned)(ks << 6)));
  }

  for (int t = 0; t < NT; ++t) {
    const char* base = lds + (unsigned)(t & 1) * 32768u;
    const char* nbase = lds + (unsigned)((t + 1) & 1) * 32768u;

#pragma unroll
    for (int ks = 0; ks < 2; ++ks)
#pragma unroll
      for (int n = 0; n < 2; ++n)
        bg[n][ks] = *reinterpret_cast<const bf16x8*>(base + (bOffG[n] ^ (unsigned)(ks << 6)));
    STAGE_A(t + 1, 1);
    SCHED();
    PRIO1();
#pragma unroll
    for (int ks = 0; ks < 2; ++ks)
#pragma unroll
      for (int m = 0; m < 4; ++m)
#pragma unroll
        for (int n = 0; n < 2; ++n)
          aU[m][n] = __builtin_amdgcn_mfma_f32_16x16x32_bf16(aLo[m][ks], bu[n][ks], aU[m][n], 0, 0, 0);
    PRIO0(); SCHED(); SBAR();

#pragma unroll
    for (int ks = 0; ks < 2; ++ks)
#pragma unroll
      for (int m = 0; m < 4; ++m)
        aHi[m][ks] = *reinterpret_cast<const bf16x8*>(base + (aOff[4 + m] ^ (unsigned)(ks << 6)));
    STAGE_B(t + 2, 0);
    SCHED();
    PRIO1();
#pragma unroll
    for (int ks = 0; ks < 2; ++ks)
#pragma unroll
      for (int m = 0; m < 4; ++m)
#pragma unroll
        for (int n = 0; n < 2; ++n)
          aG[m][n] = __builtin_amdgcn_mfma_f32_16x16x32_bf16(aLo[m][ks], bg[n][ks], aG[m][n], 0, 0, 0);
    PRIO0(); SCHED(); SBAR();

    STAGE_B(t + 2, 1);
    SCHED();
    PRIO1();
#pragma unroll
    for (int ks = 0; ks < 2; ++ks)
#pragma unroll
      for (int m = 0; m < 4; ++m)
#pragma unroll
        for (int n = 0; n < 2; ++n)
          aU[4 + m][n] = __builtin_amdgcn_mfma_f32_16x16x32_bf16(aHi[m][ks], bu[n][ks], aU[4 + m][n], 0, 0, 0);
    PRIO0(); SCHED(); SBAR();

    STAGE_A(t + 2, 0);
    VM6(); SCHED(); SBAR();
#pragma unroll
    for (int ks = 0; ks < 2; ++ks) {
#pragma unroll
      for (int m = 0; m < 4; ++m)
        aLo[m][ks] = *reinterpret_cast<const bf16x8*>(nbase + (aOff[m] ^ (unsigned)(ks << 6)));
#pragma unroll
      for (int n = 0; n < 2; ++n)
        bu[n][ks] = *reinterpret_cast<const bf16x8*>(nbase + (bOffU[n] ^ (unsigned)(ks << 6)));
    }
    SCHED();
    PRIO1();
#pragma unroll
    for (int ks = 0; ks < 2; ++ks)
#pragma unroll
      for (int m = 0; m < 4; ++m)
#pragma unroll
        for (int n = 0; n < 2; ++n)
          aG[4 + m][n] = __builtin_amdgcn_mfma_f32_16x16x32_bf16(aHi[m][ks], bg[n][ks], aG[4 + m][n], 0, 0, 0);
    PRIO0(); SCHED();
  }

#pragma unroll
  for (int m = 0; m < 8; ++m)
#pragma unroll
    for (int j = 0; j < 4; ++j) {
      const int r = wr * 128 + m * 16 + hi * 4 + j;
      if (r < nrows) {
        const size_t rowBase = (size_t)(row0 + r) * H_ + (size_t)cb * 128 + (size_t)wc * 32;
#pragma unroll
        for (int n = 0; n < 2; ++n) {
          const float u = aU[m][n][j];
          const float g = aG[m][n][j];
          act[rowBase + n * 16 + l15] = f2bf(u * (g / (1.0f + __expf(-g))));
        }
      }
    }
}

// ---------------- GEMM2: 128x128 tile, BK=64, double-buffered counted-vmcnt (R12 form, unchanged)
__global__ __launch_bounds__(256, 2) void gemm2_kernel(
    const char* __restrict__ actb, const char* __restrict__ w2b,
    const int* __restrict__ perm, const float* __restrict__ wgt,
    const int* __restrict__ meta, float* __restrict__ y) {
  __shared__ char lds[65536];  // A: buf c @ c*16K; B: 32K + c*16K
  int bid = (int)blockIdx.x;
  bid = (bid & 7) * ((int)gridDim.x >> 3) + (bid >> 3);  // 8704%8==0
  const int st = bid >> 4;     // row subtile (128 rows)
  const int cb = bid & 15;     // 128-col block of D
  const int tb = st >> 1, half = st & 1;
  if (tb >= meta[M_NT]) return;
  const int nrA = meta[M_TN + tb] - half * 128;
  if (nrA <= 0) return;
  const int nrows = (nrA < 128) ? nrA : 128;
  const int row0 = meta[M_TR + tb] + half * 128;
  const int e = meta[M_TE + tb];
  const int tid = threadIdx.x, lane = tid & 63, wid = tid >> 6;
  const int wr = wid >> 1, wc = wid & 1;
  const unsigned ldsBase = (unsigned)(unsigned long long)&lds[0];
  constexpr int NT = H_ / BK_;  // 22

  const char* aSrc[4];
  const char* bSrc[4];
  {
    const int r8 = tid >> 3;
    const unsigned colb0 = (unsigned)(tid & 7) * 16u;
#pragma unroll
    for (int i = 0; i < 4; ++i) {
      const int r = r8 + i * 32;
      const unsigned colb = colb0 ^ ((unsigned)(r & 7) << 4);
      const int rc = (r < nrows) ? r : 0;
      aSrc[i] = actb + (size_t)(row0 + rc) * (H_ * 2) + colb;
      const int brow = cb * 128 + r;
      bSrc[i] = w2b + (size_t)e * D_ * (H_ * 2) + (size_t)brow * (H_ * 2) + colb;
    }
  }

  const int l15 = lane & 15, hi = lane >> 4;
  const unsigned swz = (unsigned)(l15 & 7) << 4;
  unsigned aOff[4], bOff[4];
#pragma unroll
  for (int m = 0; m < 4; ++m) {
    const int ra = wr * 64 + m * 16 + l15;
    aOff[m] = (unsigned)(ra * 128) + (((unsigned)hi * 16u) ^ swz);
    const int rb = wc * 64 + m * 16 + l15;
    bOff[m] = 32768u + (unsigned)(rb * 128) + (((unsigned)hi * 16u) ^ swz);
  }

  f32x4 acc[4][4];
#pragma unroll
  for (int m = 0; m < 4; ++m)
#pragma unroll
    for (int n = 0; n < 4; ++n) acc[m][n] = (f32x4){0.f, 0.f, 0.f, 0.f};

  auto STAGE = [&](int t, int c) {
    const size_t kb = (size_t)t * 128;
    const unsigned dst = ldsBase + (unsigned)c * 16384u + (unsigned)tid * 16u;
#pragma unroll
    for (int i = 0; i < 4; ++i) {
      gload16(aSrc[i] + kb, dst + (unsigned)i * 4096u);
      gload16(bSrc[i] + kb, dst + 32768u + (unsigned)i * 4096u);
    }
  };

  STAGE(0, 0);
  for (int t = 0; t < NT; ++t) {
    if (t + 1 < NT) {
      STAGE(t + 1, (t + 1) & 1);
      VM8();
    } else {
      VM0();
    }
    SCHED(); SBAR();
    const char* abase = lds + (unsigned)(t & 1) * 16384u;
#pragma unroll
    for (int ks = 0; ks < 2; ++ks) {
      bf16x8 a[4], b[4];
#pragma unroll
      for (int m = 0; m < 4; ++m) {
        a[m] = *reinterpret_cast<const bf16x8*>(abase + (aOff[m] ^ (unsigned)(ks << 6)));
        b[m] = *reinterpret_cast<const bf16x8*>(abase + (bOff[m] ^ (unsigned)(ks << 6)));
      }
      PRIO1();
#pragma unroll
      for (int m = 0; m < 4; ++m)
#pragma unroll
        for (int n = 0; n < 4; ++n)
          acc[m][n] = __builtin_amdgcn_mfma_f32_16x16x32_bf16(a[m], b[n], acc[m][n], 0, 0, 0);
      PRIO0();
    }
    SCHED(); SBAR();
  }

#pragma unroll
  for (int m = 0; m < 4; ++m)
#pragma unroll
    for (int j = 0; j < 4; ++j) {
      const int r = wr * 64 + m * 16 + hi * 4 + j;
      if (r < nrows) {
        const float w = wgt[row0 + r];
        const int token = perm[row0 + r];
        float* yrow = y + (size_t)token * D_ + (size_t)cb * 128 + (size_t)wc * 64;
#pragma unroll
        for (int n = 0; n < 4; ++n)
          unsafeAtomicAdd(&yrow[n * 16 + l15], acc[m][n][j] * w);
      }
    }
}

extern "C" void kernel_launch(void* const* d_in, const int* in_sizes, int n_in,
                              void* d_out, int out_size, void* d_ws, size_t ws_size,
                              hipStream_t stream) {
  const float* x   = (const float*)d_in[0];
  const float* wts = (const float*)d_in[1];
  const int*   idx = (const int*)d_in[2];
  const float* W1  = (const float*)d_in[3];
  const float* W2  = (const float*)d_in[4];
  float* y = (float*)d_out;
  char* ws = (char*)d_ws;

  unsigned short* xb  = (unsigned short*)(ws + XB_OFF);
  unsigned short* w1b = (unsigned short*)(ws + W1B_OFF);
  unsigned short* w2b = (unsigned short*)(ws + W2B_OFF);
  unsigned short* act = (unsigned short*)(ws + ACT_OFF);
  int*   perm = (int*)(ws + PERM_OFF);
  float* wgt  = (float*)(ws + WGT_OFF);
  int*   meta = (int*)(ws + META_B);

  prep_kernel<<<2049, 1024, 0, stream>>>(x, W1, idx, wts, y, xb, w1b, meta, perm, wgt);

  gemm1_kernel<<<CVTB_ + MAXT_ * (H_ / 128), 512, 0, stream>>>(
      (const char*)xb, (const char*)w1b, perm, meta, act, W2, w2b);

  gemm2_kernel<<<MAXT_ * 2 * (D_ / 128), 256, 0, stream>>>(
      (const char*)act, (const char*)w2b, perm, wgt, meta, y);
}